// Round 11
// baseline (659.702 us; speedup 1.0000x reference)
//
#include <hip/hip_runtime.h>

typedef __bf16 bf16;
typedef __bf16 bf16x4 __attribute__((ext_vector_type(4)));
typedef __bf16 bf16x8 __attribute__((ext_vector_type(8)));
typedef float  floatx4 __attribute__((ext_vector_type(4)));

__device__ __forceinline__ floatx4 mfma16(bf16x8 a, bf16x8 b, floatx4 c) {
    return __builtin_amdgcn_mfma_f32_16x16x32_bf16(a, b, c, 0, 0, 0);
}

// ---------------- shared transpose helper (f32 src -> bf16 dst^T), 256-thread linear block ----
__device__ __forceinline__ void transpose_tile(const float* __restrict__ src,
                                               bf16* __restrict__ dst,
                                               int R, int C, int rt, int ct,
                                               float (*tile)[33]) {
    int t = threadIdx.x;
    int tx = t & 31, ty = t >> 5;   // 32 x 8
    int c0 = ct * 32, r0 = rt * 32;
    for (int i = ty; i < 32; i += 8) {
        int r = r0 + i, c = c0 + tx;
        tile[i][tx] = (r < R && c < C) ? src[r * C + c] : 0.f;
    }
    __syncthreads();
    for (int i = ty; i < 32; i += 8) {
        int r = r0 + tx, c = c0 + i;
        if (r < R && c < C) dst[(size_t)c * R + r] = (bf16)tile[tx][i];
    }
}

// ---------------- prep: qkv weight transposes + x cast, one kernel ----------------
// blocks: [0,384) WlT tiles; [384,768) WcT tiles; [768,1792) xcast
__global__ __launch_bounds__(256) void k_prep(
    const float* __restrict__ W_lqkv, const float* __restrict__ W_cqkv,
    const float* __restrict__ x,
    bf16* __restrict__ WlT, bf16* __restrict__ WcT, bf16* __restrict__ xb)
{
    __shared__ float tile[32][33];
    int b = blockIdx.x;
    if (b < 384) {
        transpose_tile(W_lqkv, WlT, 512, 768, b / 24, b % 24, tile);
    } else if (b < 768) {
        transpose_tile(W_cqkv, WcT, 512, 768, (b - 384) / 24, (b - 384) % 24, tile);
    } else {
        int i = ((b - 768) * 256 + threadIdx.x) * 8;
        float4 f0 = *(const float4*)(x + i);
        float4 f1 = *(const float4*)(x + i + 4);
        bf16x8 a;
        a[0] = (bf16)f0.x; a[1] = (bf16)f0.y; a[2] = (bf16)f0.z; a[3] = (bf16)f0.w;
        a[4] = (bf16)f1.x; a[5] = (bf16)f1.y; a[6] = (bf16)f1.z; a[7] = (bf16)f1.w;
        *(bf16x8*)(xb + i) = a;
    }
}

// ---------------- full QKV GEMM (bf16 MFMA): xb @ [W_lqkv(768) | W_cqkv(768)] ----------------
// Q pre-scaled by 0.125 (exact). lv row-major (coalesced); lvT built by k_vt2.
__global__ __launch_bounds__(256) void k_qkv(
    const bf16* __restrict__ xb,
    const bf16* __restrict__ WlT, const bf16* __restrict__ WcT,
    const float* __restrict__ b_l, const float* __restrict__ b_c,
    bf16* __restrict__ lq, bf16* __restrict__ lk, bf16* __restrict__ lv,
    bf16* __restrict__ cq, bf16* __restrict__ ck, bf16* __restrict__ cv)
{
    const int tid = threadIdx.x;
    const int wave = tid >> 6, lane = tid & 63;
    const int ln15 = lane & 15, quad = lane >> 4;
    const int m0 = blockIdx.x * 64 + wave * 16;
    const int n0 = blockIdx.y * 64;     // [0, 1536)

    floatx4 acc[4];
    for (int s = 0; s < 4; ++s) acc[s] = (floatx4){0.f, 0.f, 0.f, 0.f};

    for (int k0 = 0; k0 < 512; k0 += 32) {
        bf16x8 a = *(const bf16x8*)(xb + (m0 + ln15) * 512 + k0 + quad * 8);
        for (int s = 0; s < 4; ++s) {
            int cg = n0 + s * 16 + ln15;
            const bf16* bt = (cg < 768) ? (WlT + cg * 512) : (WcT + (cg - 768) * 512);
            bf16x8 b = *(const bf16x8*)(bt + k0 + quad * 8);
            acc[s] = mfma16(a, b, acc[s]);
        }
    }

    for (int s = 0; s < 4; ++s) {
        int cg = n0 + s * 16 + ln15;
        for (int r = 0; r < 4; ++r) {
            int row = m0 + quad * 4 + r;
            float v = acc[s][r];
            if (cg < 768) {
                v += b_l[cg];
                int qkv = cg >> 8, hh = (cg >> 6) & 3, d = cg & 63;
                if (qkv == 0)      lq[(hh * 4096 + row) * 64 + d] = (bf16)(v * 0.125f);
                else if (qkv == 1) lk[(hh * 4096 + row) * 64 + d] = (bf16)v;
                else               lv[(hh * 4096 + row) * 64 + d] = (bf16)v;
            } else {
                int c = cg - 768;
                v += b_c[c];
                int qkv = c >> 8, hh = (c >> 6) & 3, d = c & 63;
                if (qkv == 0)      cq[(hh * 4096 + row) * 64 + d] = (bf16)(v * 0.125f);
                else if (qkv == 1) ck[(hh * 4096 + row) * 64 + d] = (bf16)v;
                else               cv[(hh * 4096 + row) * 64 + d] = (bf16)v;
            }
        }
    }
}

// ---------------- saliency scores: 16 rows/block, W float4 shared across 4 rows/lane ----------
__global__ __launch_bounds__(256) void k_scores(
    const float* __restrict__ x, const float* __restrict__ Ws1,  // [512][256]
    const float* __restrict__ bs1, const float* __restrict__ Ws2,  // [256]
    const float* __restrict__ bs2, float* __restrict__ scores)
{
    __shared__ float xs[16][512];   // 32 KB
    int row0 = blockIdx.x * 16;
    int t = threadIdx.x;
    for (int i = t; i < 2048; i += 256) {
        int r = i >> 7, k4 = (i & 127) * 4;
        *(float4*)&xs[r][k4] = *(const float4*)&x[(row0 + r) * 512 + k4];
    }
    __syncthreads();
    int w = t >> 6, cb = (t & 63) * 4;
    float acc[4][4];
    #pragma unroll
    for (int rr = 0; rr < 4; ++rr)
        for (int j = 0; j < 4; ++j) acc[rr][j] = 0.f;
    #pragma unroll 2
    for (int k = 0; k < 512; ++k) {
        float4 wv = *(const float4*)(Ws1 + k * 256 + cb);
        #pragma unroll
        for (int rr = 0; rr < 4; ++rr) {
            float a = xs[w * 4 + rr][k];
            acc[rr][0] = fmaf(a, wv.x, acc[rr][0]);
            acc[rr][1] = fmaf(a, wv.y, acc[rr][1]);
            acc[rr][2] = fmaf(a, wv.z, acc[rr][2]);
            acc[rr][3] = fmaf(a, wv.w, acc[rr][3]);
        }
    }
    float b1[4] = {bs1[cb], bs1[cb + 1], bs1[cb + 2], bs1[cb + 3]};
    float w2[4] = {Ws2[cb], Ws2[cb + 1], Ws2[cb + 2], Ws2[cb + 3]};
    #pragma unroll
    for (int rr = 0; rr < 4; ++rr) {
        float s = 0.f;
        #pragma unroll
        for (int j = 0; j < 4; ++j) {
            float v = acc[rr][j] + b1[j];
            float g = 0.5f * v * (1.0f + erff(v * 0.70710678118654752f));  // exact gelu
            s = fmaf(g, w2[j], s);
        }
        s += __shfl_xor(s, 1, 64);  s += __shfl_xor(s, 2, 64);
        s += __shfl_xor(s, 4, 64);  s += __shfl_xor(s, 8, 64);
        s += __shfl_xor(s, 16, 64); s += __shfl_xor(s, 32, 64);
        if ((t & 63) == 0) scores[row0 + w * 4 + rr] = s + bs2[0];
    }
}

// ---------------- exact top-819 via histogram select ----------------
__global__ __launch_bounds__(1024) void k_topk(const float* __restrict__ scores,
                                               int* __restrict__ sel, int* __restrict__ pos) {
    __shared__ unsigned ubuf[4096];
    __shared__ unsigned cga[2048], cgb[2048];
    __shared__ int bidx[1024];
    __shared__ int ctr, bctr, Bbin;
    int tid = threadIdx.x;
    if (tid == 0) { ctr = 0; bctr = 0; }
    for (int i = tid; i < 2048; i += 1024) cga[i] = 0u;
    __syncthreads();
    for (int i = tid; i < 4096; i += 1024) {
        unsigned s = __float_as_uint(scores[i]);
        unsigned u = (s & 0x80000000u) ? ~s : (s | 0x80000000u);   // order-preserving map
        ubuf[i] = u;
        pos[i] = -1;
        atomicAdd(&cga[u >> 21], 1u);
    }
    __syncthreads();
    unsigned* src = cga; unsigned* dst = cgb;
    for (int off = 1; off < 2048; off <<= 1) {
        for (int i = tid; i < 2048; i += 1024)
            dst[i] = src[i] + ((i + off < 2048) ? src[i + off] : 0u);
        __syncthreads();
        unsigned* tmp = src; src = dst; dst = tmp;
    }
    for (int b = tid; b < 2048; b += 1024) {
        unsigned ge = src[b];
        unsigned gt = (b < 2047) ? src[b + 1] : 0u;
        if (ge >= 819u && gt < 819u) Bbin = b;
    }
    __syncthreads();
    int B = Bbin;
    int countAbove = (B < 2047) ? (int)src[B + 1] : 0;
    int need = 819 - countAbove;
    for (int i = tid; i < 4096; i += 1024) {
        int b = (int)(ubuf[i] >> 21);
        if (b > B) {
            int slot = atomicAdd(&ctr, 1);
            sel[slot] = i;
            pos[i] = slot;
        } else if (b == B) {
            int ls = atomicAdd(&bctr, 1);
            if (ls < 1024) bidx[ls] = i;
        }
    }
    __syncthreads();
    int m = bctr;
    if (m <= 1024) {
        for (int e = tid; e < m; e += 1024) {
            int i = bidx[e];
            unsigned ui = ubuf[i];
            int rank = 0;
            for (int j = 0; j < m; ++j) {
                int ij = bidx[j];
                unsigned uj = ubuf[ij];
                rank += (uj > ui || (uj == ui && ij < i)) ? 1 : 0;
            }
            if (rank < need) { int slot = countAbove + rank; sel[slot] = i; pos[i] = slot; }
        }
    } else {
        for (int i = tid; i < 4096; i += 1024) {
            if ((int)(ubuf[i] >> 21) != B) continue;
            unsigned ui = ubuf[i];
            int rank = 0;
            for (int j = 0; j < 4096; ++j) {
                if ((int)(ubuf[j] >> 21) != B) continue;
                unsigned uj = ubuf[j];
                rank += (uj > ui || (uj == ui && j < i)) ? 1 : 0;
            }
            if (rank < need) { int slot = countAbove + rank; sel[slot] = i; pos[i] = slot; }
        }
    }
}

// ---------------- vt2: lv->lvT transpose tiles + content gather with fused cv transpose ------
// blocks [0,256): lvT tile b (tr = b&63, h = b>>6), R=4096
// blocks [256,312): gather tile: hh = (b-256)/14, tile = (b-256)%14, rows tile*64..+64 of 896
__global__ __launch_bounds__(256) void k_vt2(
    const bf16* __restrict__ lv, bf16* __restrict__ lvT,
    const bf16* __restrict__ ck, const bf16* __restrict__ cv,
    const int* __restrict__ sel,
    bf16* __restrict__ ckg, bf16* __restrict__ cvgT)
{
    __shared__ bf16 tile[64][66];
    int b = blockIdx.x;
    int t = threadIdx.x;
    int lane = t & 63, grp = t >> 6;
    if (b < 256) {
        int tr = b & 63, h = b >> 6;
        const bf16* s = lv + ((size_t)h * 4096 + tr * 64) * 64;
        #pragma unroll
        for (int rr = 0; rr < 16; ++rr) {
            int row = rr * 4 + grp;
            tile[row][lane] = s[row * 64 + lane];
        }
        __syncthreads();
        bf16* d = lvT + (size_t)h * 64 * 4096 + tr * 64;
        #pragma unroll
        for (int cc = 0; cc < 16; ++cc) {
            int col = cc * 4 + grp;
            d[(size_t)col * 4096 + lane] = tile[lane][col];
        }
    } else {
        int g = b - 256;
        int hh = g / 14, tl = g % 14;
        int r0 = tl * 64;
        #pragma unroll
        for (int rr = 0; rr < 16; ++rr) {
            int row = r0 + rr * 4 + grp;
            int src = (row < 819) ? sel[row] : -1;
            bf16 kv = (src >= 0) ? ck[(hh * 4096 + src) * 64 + lane] : (bf16)0.0f;
            bf16 vv = (src >= 0) ? cv[(hh * 4096 + src) * 64 + lane] : (bf16)0.0f;
            ckg[(hh * 896 + row) * 64 + lane] = kv;
            tile[rr * 4 + grp][lane] = vv;
        }
        __syncthreads();
        bf16* d = cvgT + (size_t)hh * 64 * 896 + r0;
        #pragma unroll
        for (int cc = 0; cc < 16; ++cc) {
            int col = cc * 4 + grp;
            d[(size_t)col * 896 + lane] = tile[lane][col];
        }
    }
}

// ---------------- pass 2b (fused pass 1): TWO m-tiles per wave (32 q-rows), K/V fragments
// shared between tiles (global-load count per unit work halved; QK MFMA ILP doubled).
// Local: 8-way key split (512 keys, 8 iters). Content: one block per head, all 896 keys,
// self-normalizing (writes cob + content lsum directly).
// grid (32, 36): y<32: local head y>>3, split (y&7)*512; y>=32: content head y-32.
// 1152 blocks x 4 waves = 4608 waves ~ 4.5/SIMD under launch_bounds(256,5).
__global__ __launch_bounds__(256, 5) void k_pass2b(
    const bf16* __restrict__ lq, const bf16* __restrict__ lk, const bf16* __restrict__ lvT,
    const bf16* __restrict__ cq, const bf16* __restrict__ ckg, const bf16* __restrict__ cvgT,
    float* __restrict__ partOL,   // [8][4096][256]
    float* __restrict__ partSL,   // [8][4][4096]
    float* __restrict__ lsum,     // [8][4096] (content rows 4..7 written here)
    bf16* __restrict__ cob)       // [4096][256] normalized content O
{
    __shared__ __align__(16) bf16 pbuf[4][2][2][16 * 40];  // [wave][mt][chain]
    int wave = threadIdx.x >> 6, lane = threadIdx.x & 63;
    int ln15 = lane & 15, quad = lane >> 4;
    int m0 = blockIdx.x * 128 + wave * 16;   // m-tile 0; m-tile 1 at m0+64
    int y = blockIdx.y;
    bool local = y < 32;
    int h     = local ? (y >> 3) : (y - 32);
    int split = local ? (y & 7) : 0;
    int NV    = local ? 4096 : 896;
    int kbeg  = local ? split * 512 : 0;
    int kcnt  = local ? 512 : 896;

    const bf16* Qb = (local ? lq : cq) + h * 4096 * 64;
    const bf16* Kh = (local ? lk : ckg) + h * NV * 64;
    const bf16* Vh = (local ? lvT : cvgT) + h * 64 * NV;

    bf16x8 af[2][2];
    #pragma unroll
    for (int mt = 0; mt < 2; ++mt) {
        af[mt][0] = *(const bf16x8*)(Qb + (m0 + mt * 64 + ln15) * 64 + quad * 8);
        af[mt][1] = *(const bf16x8*)(Qb + (m0 + mt * 64 + ln15) * 64 + 32 + quad * 8);
    }

    floatx4 o[2][4];
    #pragma unroll
    for (int mt = 0; mt < 2; ++mt)
        for (int ds = 0; ds < 4; ++ds) o[mt][ds] = (floatx4){0.f, 0.f, 0.f, 0.f};
    float se[2][4] = {{0.f, 0.f, 0.f, 0.f}, {0.f, 0.f, 0.f, 0.f}};

    for (int key0 = kbeg; key0 < kbeg + kcnt; key0 += 64) {
        // QK^T + exp + lsum for both chains x both m-tiles; K fragments shared across tiles
        #pragma unroll
        for (int c = 0; c < 2; ++c) {
            int kb = key0 + c * 32;
            #pragma unroll
            for (int s = 0; s < 2; ++s) {
                int kc = kb + s * 16;
                const bf16* krow = Kh + (kc + ln15) * 64;
                bf16x8 b0 = *(const bf16x8*)(krow + quad * 8);
                bf16x8 b1 = *(const bf16x8*)(krow + 32 + quad * 8);
                bool valid = local || (kc + ln15) < 819;
                #pragma unroll
                for (int mt = 0; mt < 2; ++mt) {
                    floatx4 z0 = (floatx4){0.f, 0.f, 0.f, 0.f};
                    floatx4 z1 = (floatx4){0.f, 0.f, 0.f, 0.f};
                    z0 = mfma16(af[mt][0], b0, z0);
                    z1 = mfma16(af[mt][1], b1, z1);
                    bf16* pb = &pbuf[wave][mt][c][0];
                    #pragma unroll
                    for (int r = 0; r < 4; ++r) {
                        float p = valid ? __expf(fminf(z0[r] + z1[r], 60.f)) : 0.0f;
                        se[mt][r] += p;                                    // pass-1 fused
                        pb[(quad * 4 + r) * 40 + s * 16 + ln15] = (bf16)p; // unnormalized
                    }
                }
            }
        }
        // P@V for both chains; V fragments shared across the two m-tiles
        #pragma unroll
        for (int c = 0; c < 2; ++c) {
            int kb = key0 + c * 32;
            bf16x8 ap0 = *(const bf16x8*)(&pbuf[wave][0][c][0] + ln15 * 40 + quad * 8);
            bf16x8 ap1 = *(const bf16x8*)(&pbuf[wave][1][c][0] + ln15 * 40 + quad * 8);
            #pragma unroll
            for (int ds = 0; ds < 4; ++ds) {
                bf16x8 vb = *(const bf16x8*)(Vh + (ds * 16 + ln15) * NV + kb + quad * 8);
                o[0][ds] = mfma16(ap0, vb, o[0][ds]);
                o[1][ds] = mfma16(ap1, vb, o[1][ds]);
            }
        }
    }

    if (local) {
        float* ps = partSL + (split * 4 + h) * 4096;
        #pragma unroll
        for (int mt = 0; mt < 2; ++mt)
            for (int r = 0; r < 4; ++r) {
                float s = se[mt][r];
                s += __shfl_xor(s, 1, 64);
                s += __shfl_xor(s, 2, 64);
                s += __shfl_xor(s, 4, 64);
                s += __shfl_xor(s, 8, 64);
                if (ln15 == 0) ps[m0 + mt * 64 + quad * 4 + r] = s;
            }
        float* ob = partOL + (size_t)split * (4096 * 256);
        #pragma unroll
        for (int mt = 0; mt < 2; ++mt)
            for (int ds = 0; ds < 4; ++ds)
                for (int r = 0; r < 4; ++r)
                    ob[(m0 + mt * 64 + quad * 4 + r) * 256 + h * 64 + ds * 16 + ln15] =
                        o[mt][ds][r];
    } else {
        #pragma unroll
        for (int mt = 0; mt < 2; ++mt) {
            float rl[4];
            #pragma unroll
            for (int r = 0; r < 4; ++r) {
                float s = se[mt][r];
                s += __shfl_xor(s, 1, 64);
                s += __shfl_xor(s, 2, 64);
                s += __shfl_xor(s, 4, 64);
                s += __shfl_xor(s, 8, 64);
                if (ln15 == 0) lsum[(4 + h) * 4096 + m0 + mt * 64 + quad * 4 + r] = s;
                rl[r] = 1.0f / fmaxf(s, 1e-30f);
            }
            #pragma unroll
            for (int ds = 0; ds < 4; ++ds)
                for (int r = 0; r < 4; ++r)
                    cob[(m0 + mt * 64 + quad * 4 + r) * 256 + h * 64 + ds * 16 + ln15] =
                        (bf16)(o[mt][ds][r] * rl[r]);
        }
    }
}

// ---------------- reduce local partials (8 splits): lsum local rows + normalized lob ---------
__global__ __launch_bounds__(256) void k_reduce2(
    const float* __restrict__ partOL, const float* __restrict__ partSL,
    float* __restrict__ lsum, bf16* __restrict__ lob)
{
    int t = threadIdx.x;
    int q0 = blockIdx.x * 4;
    int r = t >> 6, cc = (t & 63) * 4;
    int q = q0 + r;
    int h = cc >> 6;

    float sl = 0.f;
    #pragma unroll
    for (int s = 0; s < 8; ++s) sl += partSL[(s * 4 + h) * 4096 + q];
    float rll = 1.0f / fmaxf(sl, 1e-30f);
    float a0 = 0.f, a1 = 0.f, a2 = 0.f, a3 = 0.f;
    #pragma unroll
    for (int s = 0; s < 8; ++s) {
        float4 v = *(const float4*)(partOL + (size_t)s * 1048576 + q * 256 + cc);
        a0 += v.x; a1 += v.y; a2 += v.z; a3 += v.w;
    }
    bf16x4 ol;
    ol[0] = (bf16)(a0 * rll); ol[1] = (bf16)(a1 * rll);
    ol[2] = (bf16)(a2 * rll); ol[3] = (bf16)(a3 * rll);
    *(bf16x4*)(lob + q * 256 + cc) = ol;

    if (t < 16) {
        int h8 = t >> 2, rr = t & 3, qq = q0 + rr;
        float s = 0.f;
        #pragma unroll
        for (int sp = 0; sp < 8; ++sp) s += partSL[(sp * 4 + h8) * 4096 + qq];
        lsum[h8 * 4096 + qq] = s;
    }
}

// ---------------- pass 2a: head-mean attn write only ----------------
// grid (64, 20): y<16: local, span y*256 (8 iters); y>=16: content, span (y-16)*224 (7 iters)
__global__ __launch_bounds__(256) void k_pass2a(
    const bf16* __restrict__ lq, const bf16* __restrict__ lk,
    const bf16* __restrict__ cq, const bf16* __restrict__ ckg,
    const float* __restrict__ lsum,
    float* __restrict__ attn_local,     // [4096][4096]
    bf16* __restrict__ pcomp)           // [4096][832] compact content probs
{
    int wave = threadIdx.x >> 6, lane = threadIdx.x & 63;
    int ln15 = lane & 15, quad = lane >> 4;
    int m0 = blockIdx.x * 64 + wave * 16;
    int y = blockIdx.y;
    bool local = y < 16;
    const bf16* Q  = local ? lq : cq;
    const bf16* Kt = local ? lk : ckg;
    int NV = local ? 4096 : 896;
    int kbeg = local ? y * 256 : (y - 16) * 224;
    int kend = kbeg + (local ? 256 : 224);
    int hbase = local ? 0 : 4;

    bf16x8 af[4][2];
    #pragma unroll
    for (int h2 = 0; h2 < 4; ++h2)
        for (int ks = 0; ks < 2; ++ks)
            af[h2][ks] = *(const bf16x8*)(Q + (h2 * 4096 + m0 + ln15) * 64 + ks * 32 + quad * 8);

    float rl[4][4];   // 0.25/denominator: head-mean factor folded in
    #pragma unroll
    for (int h2 = 0; h2 < 4; ++h2)
        for (int r = 0; r < 4; ++r)
            rl[h2][r] = 0.25f / fmaxf(lsum[(hbase + h2) * 4096 + m0 + quad * 4 + r], 1e-30f);

    for (int key0 = kbeg; key0 < kend; key0 += 32) {
        float pm[2][4] = {{0.f, 0.f, 0.f, 0.f}, {0.f, 0.f, 0.f, 0.f}};
        #pragma unroll
        for (int h2 = 0; h2 < 4; ++h2) {
            #pragma unroll
            for (int s = 0; s < 2; ++s) {
                int kc = key0 + s * 16;
                const bf16* krow = Kt + (h2 * NV + kc + ln15) * 64;
                floatx4 z0 = (floatx4){0.f, 0.f, 0.f, 0.f};
                floatx4 z1 = (floatx4){0.f, 0.f, 0.f, 0.f};
                z0 = mfma16(af[h2][0], *(const bf16x8*)(krow + quad * 8), z0);
                z1 = mfma16(af[h2][1], *(const bf16x8*)(krow + 32 + quad * 8), z1);
                bool valid = local || (kc + ln15) < 819;
                if (valid)
                    for (int r = 0; r < 4; ++r)
                        pm[s][r] += __expf(fminf(z0[r] + z1[r], 60.f)) * rl[h2][r];
            }
        }
        if (local) {
            #pragma unroll
            for (int s = 0; s < 2; ++s)
                for (int r = 0; r < 4; ++r)
                    attn_local[(m0 + quad * 4 + r) * 4096 + key0 + s * 16 + ln15] = pm[s][r];
        } else {
            #pragma unroll
            for (int s = 0; s < 2; ++s) {
                int kc = key0 + s * 16 + ln15;
                if (kc < 832)
                    for (int r = 0; r < 4; ++r)
                        pcomp[(m0 + quad * 4 + r) * 832 + kc] = (bf16)(pm[s][r]);
            }
        }
    }
}

// ---------------- expand + proj weight transposes, one kernel ----------------
// blocks [0,4096): expand row b; [4096,4224): WlpT tile; [4224,4352): WcpT tile
__global__ __launch_bounds__(256) void k_expand2(
    const bf16* __restrict__ pcomp, const int* __restrict__ pos,
    const float* __restrict__ W_lproj, const float* __restrict__ W_cproj,
    bf16* __restrict__ WlpT, bf16* __restrict__ WcpT,
    float* __restrict__ attn_content)
{
    __shared__ float tile[32][33];
    int b = blockIdx.x;
    if (b < 4096) {
        int c0 = threadIdx.x * 16;
        const bf16* prow = pcomp + b * 832;
        float vals[16];
        #pragma unroll
        for (int j = 0; j < 16; ++j) {
            int p = pos[c0 + j];
            vals[j] = (p >= 0) ? (float)prow[p] : 0.0f;
        }
        float* dst = attn_content + (size_t)b * 4096 + c0;
        *(float4*)(dst)      = (float4){vals[0], vals[1], vals[2], vals[3]};
        *(float4*)(dst + 4)  = (float4){vals[4], vals[5], vals[6], vals[7]};
        *(float4*)(dst + 8)  = (float4){vals[8], vals[9], vals[10], vals[11]};
        *(float4*)(dst + 12) = (float4){vals[12], vals[13], vals[14], vals[15]};
    } else if (b < 4224) {
        int g = b - 4096;
        transpose_tile(W_lproj, WlpT, 256, 512, g / 16, g % 16, tile);
    } else {
        int g = b - 4224;
        transpose_tile(W_cproj, WcpT, 256, 512, g / 16, g % 16, tile);
    }
}

// ---------------- output projection (bf16 MFMA, bf16 A direct) ----------------
// grid (64,16): n0 = 32-col blocks -> 4096 waves = 4 waves/SIMD.
__global__ __launch_bounds__(256) void k_proj(
    const bf16* __restrict__ lob, const bf16* __restrict__ cob,
    const bf16* __restrict__ WlpT, const bf16* __restrict__ WcpT,   // [512][256] bf16
    const float* __restrict__ bl, const float* __restrict__ bc,
    float* __restrict__ out)
{
    const int tid = threadIdx.x;
    const int wave = tid >> 6, lane = tid & 63;
    const int ln15 = lane & 15, quad = lane >> 4;
    const int m0 = blockIdx.x * 64 + wave * 16;
    const int n0 = blockIdx.y * 32;     // [0, 512)

    floatx4 acc[2];
    acc[0] = (floatx4){0.f, 0.f, 0.f, 0.f};
    acc[1] = (floatx4){0.f, 0.f, 0.f, 0.f};

    for (int k0 = 0; k0 < 256; k0 += 32) {
        bf16x8 al = *(const bf16x8*)(lob + (m0 + ln15) * 256 + k0 + quad * 8);
        bf16x8 ac = *(const bf16x8*)(cob + (m0 + ln15) * 256 + k0 + quad * 8);
        #pragma unroll
        for (int s = 0; s < 2; ++s) {
            int c = n0 + s * 16 + ln15;
            acc[s] = mfma16(al, *(const bf16x8*)(WlpT + c * 256 + k0 + quad * 8), acc[s]);
            acc[s] = mfma16(ac, *(const bf16x8*)(WcpT + c * 256 + k0 + quad * 8), acc[s]);
        }
    }
    #pragma unroll
    for (int s = 0; s < 2; ++s) {
        int c = n0 + s * 16 + ln15;
        float bias = bl[c] + bc[c];
        for (int r = 0; r < 4; ++r)
            out[(m0 + quad * 4 + r) * 512 + c] = acc[s][r] + bias;
    }
}

// ---------------- workspace layout (bytes), total 26,251,264 (proven-safe) ----------------
#define OFF_WLQKVT  0L            //  768x512 bf16
#define OFF_WCQKVT  786432L       //  768x512 bf16
#define OFF_LQ      1572864L      //  4x4096x64 bf16
#define OFF_LK      3670016L
#define OFF_LVT     5767168L
#define OFF_CQ      7864320L
#define OFF_CK      9961472L
#define OFF_CV      12058624L
#define OFF_PCOMP   9961472L      // aliases ck/cv (disjoint lifetime)
#define OFF_CKG     16777216L     //  4x896x64 bf16
#define OFF_CVGT    17235968L     //  4x64x896 bf16
#define OFF_WLPT    16777216L     //  aliases ckg (written in k_expand2, post-pass2a)
#define OFF_WCPT    17039360L     //  aliases ckg/cvgT (written in k_expand2, post-pass2a)
#define OFF_SCORES  17694720L     //  4096 f32
#define OFF_SEL     17711104L
#define OFF_POS     17715200L
#define OFF_LSUM    17731584L     //  8x4096 f32 (content rows by pass2b, local rows by reduce2)
#define OFF_LO      17862656L     //  region: xb (4MB bf16, prep..qkv) then lob (2MB bf16, reduce2..proj)
#define OFF_CO      22056960L     //  region: lv (2MB bf16, qkv..vt2) then cob (2MB bf16, pass2b..proj)
#define WS_TOTAL    26251264L
// Partials (32.5 MB) live in the attn_content output region (dead until k_expand2):
//   partOL [8][4096][256] f32 @ attn_content + 0           (8,388,608 floats)
//   partSL [8][4][4096]  f32  @ attn_content + 8,388,608   (131,072 floats)

extern "C" void kernel_launch(void* const* d_in, const int* in_sizes, int n_in,
                              void* d_out, int out_size, void* d_ws, size_t ws_size,
                              hipStream_t stream) {
    if (ws_size < (size_t)WS_TOTAL) return;  // diagnostic signature: absmax == 4.077e-2

    const float* x       = (const float*)d_in[0];
    const float* W_lqkv  = (const float*)d_in[1];
    const float* b_lqkv  = (const float*)d_in[2];
    const float* W_cqkv  = (const float*)d_in[3];
    const float* b_cqkv  = (const float*)d_in[4];
    const float* W_lproj = (const float*)d_in[5];
    const float* b_lproj = (const float*)d_in[6];
    const float* W_cproj = (const float*)d_in[7];
    const float* b_cproj = (const float*)d_in[8];
    const float* W_s1    = (const float*)d_in[9];
    const float* b_s1    = (const float*)d_in[10];
    const float* W_s2    = (const float*)d_in[11];
    const float* b_s2    = (const float*)d_in[12];

    char* ws = (char*)d_ws;
    bf16* WlqkvT  = (bf16*)(ws + OFF_WLQKVT);
    bf16* WcqkvT  = (bf16*)(ws + OFF_WCQKVT);
    bf16* lq    = (bf16*)(ws + OFF_LQ);
    bf16* lk    = (bf16*)(ws + OFF_LK);
    bf16* lvT   = (bf16*)(ws + OFF_LVT);
    bf16* cq    = (bf16*)(ws + OFF_CQ);
    bf16* ck    = (bf16*)(ws + OFF_CK);
    bf16* cv    = (bf16*)(ws + OFF_CV);
    bf16* pcomp = (bf16*)(ws + OFF_PCOMP);
    bf16* ckg   = (bf16*)(ws + OFF_CKG);
    bf16* cvgT  = (bf16*)(ws + OFF_CVGT);
    bf16* WlpT  = (bf16*)(ws + OFF_WLPT);
    bf16* WcpT  = (bf16*)(ws + OFF_WCPT);
    float* scores  = (float*)(ws + OFF_SCORES);
    int*   sel     = (int*)(ws + OFF_SEL);
    int*   pos     = (int*)(ws + OFF_POS);
    float* lsum    = (float*)(ws + OFF_LSUM);
    bf16*  xb      = (bf16*)(ws + OFF_LO);     // alias: dead once k_qkv done
    bf16*  lob     = (bf16*)(ws + OFF_LO);     // written by k_reduce2 (after xb dead)
    bf16*  lv      = (bf16*)(ws + OFF_CO);     // alias: dead once k_vt2 done
    bf16*  cob     = (bf16*)(ws + OFF_CO);     // written by k_pass2b (after lv dead)

    float* outp = (float*)d_out;
    float* attn_local   = outp + 2097152;              // 4096*512
    float* attn_content = attn_local + 4096 * 4096;
    float* partOL = attn_content;                      // scratch in output region
    float* partSL = attn_content + 8388608;

    k_prep<<<1792, 256, 0, stream>>>(W_lqkv, W_cqkv, x, WlqkvT, WcqkvT, xb);
    k_qkv<<<dim3(64, 24), 256, 0, stream>>>(xb, WlqkvT, WcqkvT, b_lqkv, b_cqkv,
                                            lq, lk, lv, cq, ck, cv);
    k_scores<<<256, 256, 0, stream>>>(x, W_s1, b_s1, W_s2, b_s2, scores);
    k_topk<<<1, 1024, 0, stream>>>(scores, sel, pos);
    k_vt2<<<312, 256, 0, stream>>>(lv, lvT, ck, cv, sel, ckg, cvgT);
    // fused attention core: 2 m-tiles/wave, shared K/V fragments, no atomics, no pre-zero
    k_pass2b<<<dim3(32, 36), 256, 0, stream>>>(lq, lk, lvT, cq, ckg, cvgT,
                                               partOL, partSL, lsum, cob);
    k_reduce2<<<1024, 256, 0, stream>>>(partOL, partSL, lsum, lob);
    k_pass2a<<<dim3(64, 20), 256, 0, stream>>>(lq, lk, cq, ckg, lsum,
                                               attn_local, pcomp);
    k_expand2<<<4352, 256, 0, stream>>>(pcomp, pos, W_lproj, W_cproj,
                                        WlpT, WcpT, attn_content);
    k_proj<<<dim3(64, 16), 256, 0, stream>>>(lob, cob, WlpT, WcpT, b_lproj, b_cproj, outp);
}

// Round 12
// 634.260 us; speedup vs baseline: 1.0401x; 1.0401x over previous
//
#include <hip/hip_runtime.h>

typedef __bf16 bf16;
typedef __bf16 bf16x4 __attribute__((ext_vector_type(4)));
typedef __bf16 bf16x8 __attribute__((ext_vector_type(8)));
typedef float  floatx4 __attribute__((ext_vector_type(4)));

__device__ __forceinline__ floatx4 mfma16(bf16x8 a, bf16x8 b, floatx4 c) {
    return __builtin_amdgcn_mfma_f32_16x16x32_bf16(a, b, c, 0, 0, 0);
}

// ---------------- shared transpose helper (f32 src -> bf16 dst^T), 256-thread linear block ----
__device__ __forceinline__ void transpose_tile(const float* __restrict__ src,
                                               bf16* __restrict__ dst,
                                               int R, int C, int rt, int ct,
                                               float (*tile)[33]) {
    int t = threadIdx.x;
    int tx = t & 31, ty = t >> 5;   // 32 x 8
    int c0 = ct * 32, r0 = rt * 32;
    for (int i = ty; i < 32; i += 8) {
        int r = r0 + i, c = c0 + tx;
        tile[i][tx] = (r < R && c < C) ? src[r * C + c] : 0.f;
    }
    __syncthreads();
    for (int i = ty; i < 32; i += 8) {
        int r = r0 + tx, c = c0 + i;
        if (r < R && c < C) dst[(size_t)c * R + r] = (bf16)tile[tx][i];
    }
}

// ---------------- prep: qkv weight transposes + x cast, one kernel ----------------
// blocks: [0,384) WlT tiles; [384,768) WcT tiles; [768,1792) xcast
__global__ __launch_bounds__(256) void k_prep(
    const float* __restrict__ W_lqkv, const float* __restrict__ W_cqkv,
    const float* __restrict__ x,
    bf16* __restrict__ WlT, bf16* __restrict__ WcT, bf16* __restrict__ xb)
{
    __shared__ float tile[32][33];
    int b = blockIdx.x;
    if (b < 384) {
        transpose_tile(W_lqkv, WlT, 512, 768, b / 24, b % 24, tile);
    } else if (b < 768) {
        transpose_tile(W_cqkv, WcT, 512, 768, (b - 384) / 24, (b - 384) % 24, tile);
    } else {
        int i = ((b - 768) * 256 + threadIdx.x) * 8;
        float4 f0 = *(const float4*)(x + i);
        float4 f1 = *(const float4*)(x + i + 4);
        bf16x8 a;
        a[0] = (bf16)f0.x; a[1] = (bf16)f0.y; a[2] = (bf16)f0.z; a[3] = (bf16)f0.w;
        a[4] = (bf16)f1.x; a[5] = (bf16)f1.y; a[6] = (bf16)f1.z; a[7] = (bf16)f1.w;
        *(bf16x8*)(xb + i) = a;
    }
}

// ---------------- full QKV GEMM (bf16 MFMA): xb @ [W_lqkv(768) | W_cqkv(768)] ----------------
// Q pre-scaled by 0.125 (exact). lv row-major (coalesced); lvT built by k_vt2.
__global__ __launch_bounds__(256) void k_qkv(
    const bf16* __restrict__ xb,
    const bf16* __restrict__ WlT, const bf16* __restrict__ WcT,
    const float* __restrict__ b_l, const float* __restrict__ b_c,
    bf16* __restrict__ lq, bf16* __restrict__ lk, bf16* __restrict__ lv,
    bf16* __restrict__ cq, bf16* __restrict__ ck, bf16* __restrict__ cv)
{
    const int tid = threadIdx.x;
    const int wave = tid >> 6, lane = tid & 63;
    const int ln15 = lane & 15, quad = lane >> 4;
    const int m0 = blockIdx.x * 64 + wave * 16;
    const int n0 = blockIdx.y * 64;     // [0, 1536)

    floatx4 acc[4];
    for (int s = 0; s < 4; ++s) acc[s] = (floatx4){0.f, 0.f, 0.f, 0.f};

    for (int k0 = 0; k0 < 512; k0 += 32) {
        bf16x8 a = *(const bf16x8*)(xb + (m0 + ln15) * 512 + k0 + quad * 8);
        for (int s = 0; s < 4; ++s) {
            int cg = n0 + s * 16 + ln15;
            const bf16* bt = (cg < 768) ? (WlT + cg * 512) : (WcT + (cg - 768) * 512);
            bf16x8 b = *(const bf16x8*)(bt + k0 + quad * 8);
            acc[s] = mfma16(a, b, acc[s]);
        }
    }

    for (int s = 0; s < 4; ++s) {
        int cg = n0 + s * 16 + ln15;
        for (int r = 0; r < 4; ++r) {
            int row = m0 + quad * 4 + r;
            float v = acc[s][r];
            if (cg < 768) {
                v += b_l[cg];
                int qkv = cg >> 8, hh = (cg >> 6) & 3, d = cg & 63;
                if (qkv == 0)      lq[(hh * 4096 + row) * 64 + d] = (bf16)(v * 0.125f);
                else if (qkv == 1) lk[(hh * 4096 + row) * 64 + d] = (bf16)v;
                else               lv[(hh * 4096 + row) * 64 + d] = (bf16)v;
            } else {
                int c = cg - 768;
                v += b_c[c];
                int qkv = c >> 8, hh = (c >> 6) & 3, d = c & 63;
                if (qkv == 0)      cq[(hh * 4096 + row) * 64 + d] = (bf16)(v * 0.125f);
                else if (qkv == 1) ck[(hh * 4096 + row) * 64 + d] = (bf16)v;
                else               cv[(hh * 4096 + row) * 64 + d] = (bf16)v;
            }
        }
    }
}

// ---------------- saliency scores: 16 rows/block, W float4 shared across 4 rows/lane ----------
__global__ __launch_bounds__(256) void k_scores(
    const float* __restrict__ x, const float* __restrict__ Ws1,  // [512][256]
    const float* __restrict__ bs1, const float* __restrict__ Ws2,  // [256]
    const float* __restrict__ bs2, float* __restrict__ scores)
{
    __shared__ float xs[16][512];   // 32 KB
    int row0 = blockIdx.x * 16;
    int t = threadIdx.x;
    for (int i = t; i < 2048; i += 256) {
        int r = i >> 7, k4 = (i & 127) * 4;
        *(float4*)&xs[r][k4] = *(const float4*)&x[(row0 + r) * 512 + k4];
    }
    __syncthreads();
    int w = t >> 6, cb = (t & 63) * 4;
    float acc[4][4];
    #pragma unroll
    for (int rr = 0; rr < 4; ++rr)
        for (int j = 0; j < 4; ++j) acc[rr][j] = 0.f;
    #pragma unroll 2
    for (int k = 0; k < 512; ++k) {
        float4 wv = *(const float4*)(Ws1 + k * 256 + cb);
        #pragma unroll
        for (int rr = 0; rr < 4; ++rr) {
            float a = xs[w * 4 + rr][k];
            acc[rr][0] = fmaf(a, wv.x, acc[rr][0]);
            acc[rr][1] = fmaf(a, wv.y, acc[rr][1]);
            acc[rr][2] = fmaf(a, wv.z, acc[rr][2]);
            acc[rr][3] = fmaf(a, wv.w, acc[rr][3]);
        }
    }
    float b1[4] = {bs1[cb], bs1[cb + 1], bs1[cb + 2], bs1[cb + 3]};
    float w2[4] = {Ws2[cb], Ws2[cb + 1], Ws2[cb + 2], Ws2[cb + 3]};
    #pragma unroll
    for (int rr = 0; rr < 4; ++rr) {
        float s = 0.f;
        #pragma unroll
        for (int j = 0; j < 4; ++j) {
            float v = acc[rr][j] + b1[j];
            float g = 0.5f * v * (1.0f + erff(v * 0.70710678118654752f));  // exact gelu
            s = fmaf(g, w2[j], s);
        }
        s += __shfl_xor(s, 1, 64);  s += __shfl_xor(s, 2, 64);
        s += __shfl_xor(s, 4, 64);  s += __shfl_xor(s, 8, 64);
        s += __shfl_xor(s, 16, 64); s += __shfl_xor(s, 32, 64);
        if ((t & 63) == 0) scores[row0 + w * 4 + rr] = s + bs2[0];
    }
}

// ---------------- exact top-819 via histogram select ----------------
__global__ __launch_bounds__(1024) void k_topk(const float* __restrict__ scores,
                                               int* __restrict__ sel, int* __restrict__ pos) {
    __shared__ unsigned ubuf[4096];
    __shared__ unsigned cga[2048], cgb[2048];
    __shared__ int bidx[1024];
    __shared__ int ctr, bctr, Bbin;
    int tid = threadIdx.x;
    if (tid == 0) { ctr = 0; bctr = 0; }
    for (int i = tid; i < 2048; i += 1024) cga[i] = 0u;
    __syncthreads();
    for (int i = tid; i < 4096; i += 1024) {
        unsigned s = __float_as_uint(scores[i]);
        unsigned u = (s & 0x80000000u) ? ~s : (s | 0x80000000u);   // order-preserving map
        ubuf[i] = u;
        pos[i] = -1;
        atomicAdd(&cga[u >> 21], 1u);
    }
    __syncthreads();
    unsigned* src = cga; unsigned* dst = cgb;
    for (int off = 1; off < 2048; off <<= 1) {
        for (int i = tid; i < 2048; i += 1024)
            dst[i] = src[i] + ((i + off < 2048) ? src[i + off] : 0u);
        __syncthreads();
        unsigned* tmp = src; src = dst; dst = tmp;
    }
    for (int b = tid; b < 2048; b += 1024) {
        unsigned ge = src[b];
        unsigned gt = (b < 2047) ? src[b + 1] : 0u;
        if (ge >= 819u && gt < 819u) Bbin = b;
    }
    __syncthreads();
    int B = Bbin;
    int countAbove = (B < 2047) ? (int)src[B + 1] : 0;
    int need = 819 - countAbove;
    for (int i = tid; i < 4096; i += 1024) {
        int b = (int)(ubuf[i] >> 21);
        if (b > B) {
            int slot = atomicAdd(&ctr, 1);
            sel[slot] = i;
            pos[i] = slot;
        } else if (b == B) {
            int ls = atomicAdd(&bctr, 1);
            if (ls < 1024) bidx[ls] = i;
        }
    }
    __syncthreads();
    int m = bctr;
    if (m <= 1024) {
        for (int e = tid; e < m; e += 1024) {
            int i = bidx[e];
            unsigned ui = ubuf[i];
            int rank = 0;
            for (int j = 0; j < m; ++j) {
                int ij = bidx[j];
                unsigned uj = ubuf[ij];
                rank += (uj > ui || (uj == ui && ij < i)) ? 1 : 0;
            }
            if (rank < need) { int slot = countAbove + rank; sel[slot] = i; pos[i] = slot; }
        }
    } else {
        for (int i = tid; i < 4096; i += 1024) {
            if ((int)(ubuf[i] >> 21) != B) continue;
            unsigned ui = ubuf[i];
            int rank = 0;
            for (int j = 0; j < 4096; ++j) {
                if ((int)(ubuf[j] >> 21) != B) continue;
                unsigned uj = ubuf[j];
                rank += (uj > ui || (uj == ui && j < i)) ? 1 : 0;
            }
            if (rank < need) { int slot = countAbove + rank; sel[slot] = i; pos[i] = slot; }
        }
    }
}

// ---------------- vt2: lv->lvT transpose tiles + content gather with fused cv transpose ------
// blocks [0,256): lvT tile b (tr = b&63, h = b>>6), R=4096
// blocks [256,312): gather tile: hh = (b-256)/14, tile = (b-256)%14, rows tile*64..+64 of 896
__global__ __launch_bounds__(256) void k_vt2(
    const bf16* __restrict__ lv, bf16* __restrict__ lvT,
    const bf16* __restrict__ ck, const bf16* __restrict__ cv,
    const int* __restrict__ sel,
    bf16* __restrict__ ckg, bf16* __restrict__ cvgT)
{
    __shared__ bf16 tile[64][66];
    int b = blockIdx.x;
    int t = threadIdx.x;
    int lane = t & 63, grp = t >> 6;
    if (b < 256) {
        int tr = b & 63, h = b >> 6;
        const bf16* s = lv + ((size_t)h * 4096 + tr * 64) * 64;
        #pragma unroll
        for (int rr = 0; rr < 16; ++rr) {
            int row = rr * 4 + grp;
            tile[row][lane] = s[row * 64 + lane];
        }
        __syncthreads();
        bf16* d = lvT + (size_t)h * 64 * 4096 + tr * 64;
        #pragma unroll
        for (int cc = 0; cc < 16; ++cc) {
            int col = cc * 4 + grp;
            d[(size_t)col * 4096 + lane] = tile[lane][col];
        }
    } else {
        int g = b - 256;
        int hh = g / 14, tl = g % 14;
        int r0 = tl * 64;
        #pragma unroll
        for (int rr = 0; rr < 16; ++rr) {
            int row = r0 + rr * 4 + grp;
            int src = (row < 819) ? sel[row] : -1;
            bf16 kv = (src >= 0) ? ck[(hh * 4096 + src) * 64 + lane] : (bf16)0.0f;
            bf16 vv = (src >= 0) ? cv[(hh * 4096 + src) * 64 + lane] : (bf16)0.0f;
            ckg[(hh * 896 + row) * 64 + lane] = kv;
            tile[rr * 4 + grp][lane] = vv;
        }
        __syncthreads();
        bf16* d = cvgT + (size_t)hh * 64 * 896 + r0;
        #pragma unroll
        for (int cc = 0; cc < 16; ++cc) {
            int col = cc * 4 + grp;
            d[(size_t)col * 896 + lane] = tile[lane][col];
        }
    }
}

// ---------------- pass 2b (fused pass 1): TWO m-tiles per wave (32 q-rows), K/V fragments
// shared between tiles. R11 lesson: launch_bounds(256,5) caps regs at ~96 -> spilled
// (WRITE_SIZE 257MB of scratch traffic). Fix: (256,4) -> 128-reg budget, no spill.
// Local: 8-way key split (512 keys, 8 iters). Content: one block per head, all 896 keys,
// self-normalizing (writes cob + content lsum directly).
// grid (32, 36): y<32: local head y>>3, split (y&7)*512; y>=32: content head y-32.
__global__ __launch_bounds__(256, 4) void k_pass2b(
    const bf16* __restrict__ lq, const bf16* __restrict__ lk, const bf16* __restrict__ lvT,
    const bf16* __restrict__ cq, const bf16* __restrict__ ckg, const bf16* __restrict__ cvgT,
    float* __restrict__ partOL,   // [8][4096][256]
    float* __restrict__ partSL,   // [8][4][4096]
    float* __restrict__ lsum,     // [8][4096] (content rows 4..7 written here)
    bf16* __restrict__ cob)       // [4096][256] normalized content O
{
    __shared__ __align__(16) bf16 pbuf[4][2][2][16 * 40];  // [wave][mt][chain]
    int wave = threadIdx.x >> 6, lane = threadIdx.x & 63;
    int ln15 = lane & 15, quad = lane >> 4;
    int m0 = blockIdx.x * 128 + wave * 16;   // m-tile 0; m-tile 1 at m0+64
    int y = blockIdx.y;
    bool local = y < 32;
    int h     = local ? (y >> 3) : (y - 32);
    int split = local ? (y & 7) : 0;
    int NV    = local ? 4096 : 896;
    int kbeg  = local ? split * 512 : 0;
    int kcnt  = local ? 512 : 896;

    const bf16* Qb = (local ? lq : cq) + h * 4096 * 64;
    const bf16* Kh = (local ? lk : ckg) + h * NV * 64;
    const bf16* Vh = (local ? lvT : cvgT) + h * 64 * NV;

    bf16x8 af[2][2];
    #pragma unroll
    for (int mt = 0; mt < 2; ++mt) {
        af[mt][0] = *(const bf16x8*)(Qb + (m0 + mt * 64 + ln15) * 64 + quad * 8);
        af[mt][1] = *(const bf16x8*)(Qb + (m0 + mt * 64 + ln15) * 64 + 32 + quad * 8);
    }

    floatx4 o[2][4];
    #pragma unroll
    for (int mt = 0; mt < 2; ++mt)
        for (int ds = 0; ds < 4; ++ds) o[mt][ds] = (floatx4){0.f, 0.f, 0.f, 0.f};
    float se[2][4] = {{0.f, 0.f, 0.f, 0.f}, {0.f, 0.f, 0.f, 0.f}};

    for (int key0 = kbeg; key0 < kbeg + kcnt; key0 += 64) {
        // QK^T + exp + lsum for both chains x both m-tiles; K fragments shared across tiles
        #pragma unroll
        for (int c = 0; c < 2; ++c) {
            int kb = key0 + c * 32;
            #pragma unroll
            for (int s = 0; s < 2; ++s) {
                int kc = kb + s * 16;
                const bf16* krow = Kh + (kc + ln15) * 64;
                bf16x8 b0 = *(const bf16x8*)(krow + quad * 8);
                bf16x8 b1 = *(const bf16x8*)(krow + 32 + quad * 8);
                bool valid = local || (kc + ln15) < 819;
                #pragma unroll
                for (int mt = 0; mt < 2; ++mt) {
                    floatx4 z0 = (floatx4){0.f, 0.f, 0.f, 0.f};
                    floatx4 z1 = (floatx4){0.f, 0.f, 0.f, 0.f};
                    z0 = mfma16(af[mt][0], b0, z0);
                    z1 = mfma16(af[mt][1], b1, z1);
                    bf16* pb = &pbuf[wave][mt][c][0];
                    #pragma unroll
                    for (int r = 0; r < 4; ++r) {
                        float p = valid ? __expf(fminf(z0[r] + z1[r], 60.f)) : 0.0f;
                        se[mt][r] += p;                                    // pass-1 fused
                        pb[(quad * 4 + r) * 40 + s * 16 + ln15] = (bf16)p; // unnormalized
                    }
                }
            }
        }
        // P@V for both chains; V fragments shared across the two m-tiles
        #pragma unroll
        for (int c = 0; c < 2; ++c) {
            int kb = key0 + c * 32;
            bf16x8 ap0 = *(const bf16x8*)(&pbuf[wave][0][c][0] + ln15 * 40 + quad * 8);
            bf16x8 ap1 = *(const bf16x8*)(&pbuf[wave][1][c][0] + ln15 * 40 + quad * 8);
            #pragma unroll
            for (int ds = 0; ds < 4; ++ds) {
                bf16x8 vb = *(const bf16x8*)(Vh + (ds * 16 + ln15) * NV + kb + quad * 8);
                o[0][ds] = mfma16(ap0, vb, o[0][ds]);
                o[1][ds] = mfma16(ap1, vb, o[1][ds]);
            }
        }
    }

    if (local) {
        float* ps = partSL + (split * 4 + h) * 4096;
        #pragma unroll
        for (int mt = 0; mt < 2; ++mt)
            for (int r = 0; r < 4; ++r) {
                float s = se[mt][r];
                s += __shfl_xor(s, 1, 64);
                s += __shfl_xor(s, 2, 64);
                s += __shfl_xor(s, 4, 64);
                s += __shfl_xor(s, 8, 64);
                if (ln15 == 0) ps[m0 + mt * 64 + quad * 4 + r] = s;
            }
        float* ob = partOL + (size_t)split * (4096 * 256);
        #pragma unroll
        for (int mt = 0; mt < 2; ++mt)
            for (int ds = 0; ds < 4; ++ds)
                for (int r = 0; r < 4; ++r)
                    ob[(m0 + mt * 64 + quad * 4 + r) * 256 + h * 64 + ds * 16 + ln15] =
                        o[mt][ds][r];
    } else {
        #pragma unroll
        for (int mt = 0; mt < 2; ++mt) {
            float rl[4];
            #pragma unroll
            for (int r = 0; r < 4; ++r) {
                float s = se[mt][r];
                s += __shfl_xor(s, 1, 64);
                s += __shfl_xor(s, 2, 64);
                s += __shfl_xor(s, 4, 64);
                s += __shfl_xor(s, 8, 64);
                if (ln15 == 0) lsum[(4 + h) * 4096 + m0 + mt * 64 + quad * 4 + r] = s;
                rl[r] = 1.0f / fmaxf(s, 1e-30f);
            }
            #pragma unroll
            for (int ds = 0; ds < 4; ++ds)
                for (int r = 0; r < 4; ++r)
                    cob[(m0 + mt * 64 + quad * 4 + r) * 256 + h * 64 + ds * 16 + ln15] =
                        (bf16)(o[mt][ds][r] * rl[r]);
        }
    }
}

// ---------------- reduce local partials (8 splits): lsum local rows + normalized lob ---------
__global__ __launch_bounds__(256) void k_reduce2(
    const float* __restrict__ partOL, const float* __restrict__ partSL,
    float* __restrict__ lsum, bf16* __restrict__ lob)
{
    int t = threadIdx.x;
    int q0 = blockIdx.x * 4;
    int r = t >> 6, cc = (t & 63) * 4;
    int q = q0 + r;
    int h = cc >> 6;

    float sl = 0.f;
    #pragma unroll
    for (int s = 0; s < 8; ++s) sl += partSL[(s * 4 + h) * 4096 + q];
    float rll = 1.0f / fmaxf(sl, 1e-30f);
    float a0 = 0.f, a1 = 0.f, a2 = 0.f, a3 = 0.f;
    #pragma unroll
    for (int s = 0; s < 8; ++s) {
        float4 v = *(const float4*)(partOL + (size_t)s * 1048576 + q * 256 + cc);
        a0 += v.x; a1 += v.y; a2 += v.z; a3 += v.w;
    }
    bf16x4 ol;
    ol[0] = (bf16)(a0 * rll); ol[1] = (bf16)(a1 * rll);
    ol[2] = (bf16)(a2 * rll); ol[3] = (bf16)(a3 * rll);
    *(bf16x4*)(lob + q * 256 + cc) = ol;

    if (t < 16) {
        int h8 = t >> 2, rr = t & 3, qq = q0 + rr;
        float s = 0.f;
        #pragma unroll
        for (int sp = 0; sp < 8; ++sp) s += partSL[(sp * 4 + h8) * 4096 + qq];
        lsum[h8 * 4096 + qq] = s;
    }
}

// ---------------- pass 2a: head-mean attn write only ----------------
// grid (64, 20): y<16: local, span y*256 (8 iters); y>=16: content, span (y-16)*224 (7 iters)
__global__ __launch_bounds__(256) void k_pass2a(
    const bf16* __restrict__ lq, const bf16* __restrict__ lk,
    const bf16* __restrict__ cq, const bf16* __restrict__ ckg,
    const float* __restrict__ lsum,
    float* __restrict__ attn_local,     // [4096][4096]
    bf16* __restrict__ pcomp)           // [4096][832] compact content probs
{
    int wave = threadIdx.x >> 6, lane = threadIdx.x & 63;
    int ln15 = lane & 15, quad = lane >> 4;
    int m0 = blockIdx.x * 64 + wave * 16;
    int y = blockIdx.y;
    bool local = y < 16;
    const bf16* Q  = local ? lq : cq;
    const bf16* Kt = local ? lk : ckg;
    int NV = local ? 4096 : 896;
    int kbeg = local ? y * 256 : (y - 16) * 224;
    int kend = kbeg + (local ? 256 : 224);
    int hbase = local ? 0 : 4;

    bf16x8 af[4][2];
    #pragma unroll
    for (int h2 = 0; h2 < 4; ++h2)
        for (int ks = 0; ks < 2; ++ks)
            af[h2][ks] = *(const bf16x8*)(Q + (h2 * 4096 + m0 + ln15) * 64 + ks * 32 + quad * 8);

    float rl[4][4];   // 0.25/denominator: head-mean factor folded in
    #pragma unroll
    for (int h2 = 0; h2 < 4; ++h2)
        for (int r = 0; r < 4; ++r)
            rl[h2][r] = 0.25f / fmaxf(lsum[(hbase + h2) * 4096 + m0 + quad * 4 + r], 1e-30f);

    for (int key0 = kbeg; key0 < kend; key0 += 32) {
        float pm[2][4] = {{0.f, 0.f, 0.f, 0.f}, {0.f, 0.f, 0.f, 0.f}};
        #pragma unroll
        for (int h2 = 0; h2 < 4; ++h2) {
            #pragma unroll
            for (int s = 0; s < 2; ++s) {
                int kc = key0 + s * 16;
                const bf16* krow = Kt + (h2 * NV + kc + ln15) * 64;
                floatx4 z0 = (floatx4){0.f, 0.f, 0.f, 0.f};
                floatx4 z1 = (floatx4){0.f, 0.f, 0.f, 0.f};
                z0 = mfma16(af[h2][0], *(const bf16x8*)(krow + quad * 8), z0);
                z1 = mfma16(af[h2][1], *(const bf16x8*)(krow + 32 + quad * 8), z1);
                bool valid = local || (kc + ln15) < 819;
                if (valid)
                    for (int r = 0; r < 4; ++r)
                        pm[s][r] += __expf(fminf(z0[r] + z1[r], 60.f)) * rl[h2][r];
            }
        }
        if (local) {
            #pragma unroll
            for (int s = 0; s < 2; ++s)
                for (int r = 0; r < 4; ++r)
                    attn_local[(m0 + quad * 4 + r) * 4096 + key0 + s * 16 + ln15] = pm[s][r];
        } else {
            #pragma unroll
            for (int s = 0; s < 2; ++s) {
                int kc = key0 + s * 16 + ln15;
                if (kc < 832)
                    for (int r = 0; r < 4; ++r)
                        pcomp[(m0 + quad * 4 + r) * 832 + kc] = (bf16)(pm[s][r]);
            }
        }
    }
}

// ---------------- expand + proj weight transposes, one kernel ----------------
// blocks [0,4096): expand row b; [4096,4224): WlpT tile; [4224,4352): WcpT tile
__global__ __launch_bounds__(256) void k_expand2(
    const bf16* __restrict__ pcomp, const int* __restrict__ pos,
    const float* __restrict__ W_lproj, const float* __restrict__ W_cproj,
    bf16* __restrict__ WlpT, bf16* __restrict__ WcpT,
    float* __restrict__ attn_content)
{
    __shared__ float tile[32][33];
    int b = blockIdx.x;
    if (b < 4096) {
        int c0 = threadIdx.x * 16;
        const bf16* prow = pcomp + b * 832;
        float vals[16];
        #pragma unroll
        for (int j = 0; j < 16; ++j) {
            int p = pos[c0 + j];
            vals[j] = (p >= 0) ? (float)prow[p] : 0.0f;
        }
        float* dst = attn_content + (size_t)b * 4096 + c0;
        *(float4*)(dst)      = (float4){vals[0], vals[1], vals[2], vals[3]};
        *(float4*)(dst + 4)  = (float4){vals[4], vals[5], vals[6], vals[7]};
        *(float4*)(dst + 8)  = (float4){vals[8], vals[9], vals[10], vals[11]};
        *(float4*)(dst + 12) = (float4){vals[12], vals[13], vals[14], vals[15]};
    } else if (b < 4224) {
        int g = b - 4096;
        transpose_tile(W_lproj, WlpT, 256, 512, g / 16, g % 16, tile);
    } else {
        int g = b - 4224;
        transpose_tile(W_cproj, WcpT, 256, 512, g / 16, g % 16, tile);
    }
}

// ---------------- output projection (bf16 MFMA, bf16 A direct) ----------------
// grid (64,16): n0 = 32-col blocks -> 4096 waves = 4 waves/SIMD.
__global__ __launch_bounds__(256) void k_proj(
    const bf16* __restrict__ lob, const bf16* __restrict__ cob,
    const bf16* __restrict__ WlpT, const bf16* __restrict__ WcpT,   // [512][256] bf16
    const float* __restrict__ bl, const float* __restrict__ bc,
    float* __restrict__ out)
{
    const int tid = threadIdx.x;
    const int wave = tid >> 6, lane = tid & 63;
    const int ln15 = lane & 15, quad = lane >> 4;
    const int m0 = blockIdx.x * 64 + wave * 16;
    const int n0 = blockIdx.y * 32;     // [0, 512)

    floatx4 acc[2];
    acc[0] = (floatx4){0.f, 0.f, 0.f, 0.f};
    acc[1] = (floatx4){0.f, 0.f, 0.f, 0.f};

    for (int k0 = 0; k0 < 256; k0 += 32) {
        bf16x8 al = *(const bf16x8*)(lob + (m0 + ln15) * 256 + k0 + quad * 8);
        bf16x8 ac = *(const bf16x8*)(cob + (m0 + ln15) * 256 + k0 + quad * 8);
        #pragma unroll
        for (int s = 0; s < 2; ++s) {
            int c = n0 + s * 16 + ln15;
            acc[s] = mfma16(al, *(const bf16x8*)(WlpT + c * 256 + k0 + quad * 8), acc[s]);
            acc[s] = mfma16(ac, *(const bf16x8*)(WcpT + c * 256 + k0 + quad * 8), acc[s]);
        }
    }
    #pragma unroll
    for (int s = 0; s < 2; ++s) {
        int c = n0 + s * 16 + ln15;
        float bias = bl[c] + bc[c];
        for (int r = 0; r < 4; ++r)
            out[(m0 + quad * 4 + r) * 512 + c] = acc[s][r] + bias;
    }
}

// ---------------- workspace layout (bytes), total 26,251,264 (proven-safe) ----------------
#define OFF_WLQKVT  0L            //  768x512 bf16
#define OFF_WCQKVT  786432L       //  768x512 bf16
#define OFF_LQ      1572864L      //  4x4096x64 bf16
#define OFF_LK      3670016L
#define OFF_LVT     5767168L
#define OFF_CQ      7864320L
#define OFF_CK      9961472L
#define OFF_CV      12058624L
#define OFF_PCOMP   9961472L      // aliases ck/cv (disjoint lifetime)
#define OFF_CKG     16777216L     //  4x896x64 bf16
#define OFF_CVGT    17235968L     //  4x64x896 bf16
#define OFF_WLPT    16777216L     //  aliases ckg (written in k_expand2, post-pass2a)
#define OFF_WCPT    17039360L     //  aliases ckg/cvgT (written in k_expand2, post-pass2a)
#define OFF_SCORES  17694720L     //  4096 f32
#define OFF_SEL     17711104L
#define OFF_POS     17715200L
#define OFF_LSUM    17731584L     //  8x4096 f32 (content rows by pass2b, local rows by reduce2)
#define OFF_LO      17862656L     //  region: xb (4MB bf16, prep..qkv) then lob (2MB bf16, reduce2..proj)
#define OFF_CO      22056960L     //  region: lv (2MB bf16, qkv..vt2) then cob (2MB bf16, pass2b..proj)
#define WS_TOTAL    26251264L
// Partials (32.5 MB) live in the attn_content output region (dead until k_expand2):
//   partOL [8][4096][256] f32 @ attn_content + 0           (8,388,608 floats)
//   partSL [8][4][4096]  f32  @ attn_content + 8,388,608   (131,072 floats)

extern "C" void kernel_launch(void* const* d_in, const int* in_sizes, int n_in,
                              void* d_out, int out_size, void* d_ws, size_t ws_size,
                              hipStream_t stream) {
    if (ws_size < (size_t)WS_TOTAL) return;  // diagnostic signature: absmax == 4.077e-2

    const float* x       = (const float*)d_in[0];
    const float* W_lqkv  = (const float*)d_in[1];
    const float* b_lqkv  = (const float*)d_in[2];
    const float* W_cqkv  = (const float*)d_in[3];
    const float* b_cqkv  = (const float*)d_in[4];
    const float* W_lproj = (const float*)d_in[5];
    const float* b_lproj = (const float*)d_in[6];
    const float* W_cproj = (const float*)d_in[7];
    const float* b_cproj = (const float*)d_in[8];
    const float* W_s1    = (const float*)d_in[9];
    const float* b_s1    = (const float*)d_in[10];
    const float* W_s2    = (const float*)d_in[11];
    const float* b_s2    = (const float*)d_in[12];

    char* ws = (char*)d_ws;
    bf16* WlqkvT  = (bf16*)(ws + OFF_WLQKVT);
    bf16* WcqkvT  = (bf16*)(ws + OFF_WCQKVT);
    bf16* lq    = (bf16*)(ws + OFF_LQ);
    bf16* lk    = (bf16*)(ws + OFF_LK);
    bf16* lvT   = (bf16*)(ws + OFF_LVT);
    bf16* cq    = (bf16*)(ws + OFF_CQ);
    bf16* ck    = (bf16*)(ws + OFF_CK);
    bf16* cv    = (bf16*)(ws + OFF_CV);
    bf16* pcomp = (bf16*)(ws + OFF_PCOMP);
    bf16* ckg   = (bf16*)(ws + OFF_CKG);
    bf16* cvgT  = (bf16*)(ws + OFF_CVGT);
    bf16* WlpT  = (bf16*)(ws + OFF_WLPT);
    bf16* WcpT  = (bf16*)(ws + OFF_WCPT);
    float* scores  = (float*)(ws + OFF_SCORES);
    int*   sel     = (int*)(ws + OFF_SEL);
    int*   pos     = (int*)(ws + OFF_POS);
    float* lsum    = (float*)(ws + OFF_LSUM);
    bf16*  xb      = (bf16*)(ws + OFF_LO);     // alias: dead once k_qkv done
    bf16*  lob     = (bf16*)(ws + OFF_LO);     // written by k_reduce2 (after xb dead)
    bf16*  lv      = (bf16*)(ws + OFF_CO);     // alias: dead once k_vt2 done
    bf16*  cob     = (bf16*)(ws + OFF_CO);     // written by k_pass2b (after lv dead)

    float* outp = (float*)d_out;
    float* attn_local   = outp + 2097152;              // 4096*512
    float* attn_content = attn_local + 4096 * 4096;
    float* partOL = attn_content;                      // scratch in output region
    float* partSL = attn_content + 8388608;

    k_prep<<<1792, 256, 0, stream>>>(W_lqkv, W_cqkv, x, WlqkvT, WcqkvT, xb);
    k_qkv<<<dim3(64, 24), 256, 0, stream>>>(xb, WlqkvT, WcqkvT, b_lqkv, b_cqkv,
                                            lq, lk, lv, cq, ck, cv);
    k_scores<<<256, 256, 0, stream>>>(x, W_s1, b_s1, W_s2, b_s2, scores);
    k_topk<<<1, 1024, 0, stream>>>(scores, sel, pos);
    k_vt2<<<312, 256, 0, stream>>>(lv, lvT, ck, cv, sel, ckg, cvgT);
    // fused attention core: 2 m-tiles/wave, shared K/V fragments, no atomics, no pre-zero
    k_pass2b<<<dim3(32, 36), 256, 0, stream>>>(lq, lk, lvT, cq, ckg, cvgT,
                                               partOL, partSL, lsum, cob);
    k_reduce2<<<1024, 256, 0, stream>>>(partOL, partSL, lsum, lob);
    k_pass2a<<<dim3(64, 20), 256, 0, stream>>>(lq, lk, cq, ckg, lsum,
                                               attn_local, pcomp);
    k_expand2<<<4352, 256, 0, stream>>>(pcomp, pos, W_lproj, W_cproj,
                                        WlpT, WcpT, attn_content);
    k_proj<<<dim3(64, 16), 256, 0, stream>>>(lob, cob, WlpT, WcpT, b_lproj, b_cproj, outp);
}

// Round 13
// 589.982 us; speedup vs baseline: 1.1182x; 1.0750x over previous
//
#include <hip/hip_runtime.h>

typedef __bf16 bf16;
typedef __bf16 bf16x4 __attribute__((ext_vector_type(4)));
typedef __bf16 bf16x8 __attribute__((ext_vector_type(8)));
typedef float  floatx4 __attribute__((ext_vector_type(4)));

__device__ __forceinline__ floatx4 mfma16(bf16x8 a, bf16x8 b, floatx4 c) {
    return __builtin_amdgcn_mfma_f32_16x16x32_bf16(a, b, c, 0, 0, 0);
}

// ---------------- shared transpose helper (f32 src -> bf16 dst^T), 256-thread linear block ----
__device__ __forceinline__ void transpose_tile(const float* __restrict__ src,
                                               bf16* __restrict__ dst,
                                               int R, int C, int rt, int ct,
                                               float (*tile)[33]) {
    int t = threadIdx.x;
    int tx = t & 31, ty = t >> 5;   // 32 x 8
    int c0 = ct * 32, r0 = rt * 32;
    for (int i = ty; i < 32; i += 8) {
        int r = r0 + i, c = c0 + tx;
        tile[i][tx] = (r < R && c < C) ? src[r * C + c] : 0.f;
    }
    __syncthreads();
    for (int i = ty; i < 32; i += 8) {
        int r = r0 + tx, c = c0 + i;
        if (r < R && c < C) dst[(size_t)c * R + r] = (bf16)tile[tx][i];
    }
}

// ---------------- prep: qkv weight transposes + x cast, one kernel ----------------
// blocks: [0,384) WlT tiles; [384,768) WcT tiles; [768,1792) xcast
__global__ __launch_bounds__(256) void k_prep(
    const float* __restrict__ W_lqkv, const float* __restrict__ W_cqkv,
    const float* __restrict__ x,
    bf16* __restrict__ WlT, bf16* __restrict__ WcT, bf16* __restrict__ xb)
{
    __shared__ float tile[32][33];
    int b = blockIdx.x;
    if (b < 384) {
        transpose_tile(W_lqkv, WlT, 512, 768, b / 24, b % 24, tile);
    } else if (b < 768) {
        transpose_tile(W_cqkv, WcT, 512, 768, (b - 384) / 24, (b - 384) % 24, tile);
    } else {
        int i = ((b - 768) * 256 + threadIdx.x) * 8;
        float4 f0 = *(const float4*)(x + i);
        float4 f1 = *(const float4*)(x + i + 4);
        bf16x8 a;
        a[0] = (bf16)f0.x; a[1] = (bf16)f0.y; a[2] = (bf16)f0.z; a[3] = (bf16)f0.w;
        a[4] = (bf16)f1.x; a[5] = (bf16)f1.y; a[6] = (bf16)f1.z; a[7] = (bf16)f1.w;
        *(bf16x8*)(xb + i) = a;
    }
}

// ---------------- full QKV GEMM (bf16 MFMA): xb @ [W_lqkv(768) | W_cqkv(768)] ----------------
// Q pre-scaled by 0.125 (exact). lv row-major (coalesced); lvT built by k_vt2.
__global__ __launch_bounds__(256) void k_qkv(
    const bf16* __restrict__ xb,
    const bf16* __restrict__ WlT, const bf16* __restrict__ WcT,
    const float* __restrict__ b_l, const float* __restrict__ b_c,
    bf16* __restrict__ lq, bf16* __restrict__ lk, bf16* __restrict__ lv,
    bf16* __restrict__ cq, bf16* __restrict__ ck, bf16* __restrict__ cv)
{
    const int tid = threadIdx.x;
    const int wave = tid >> 6, lane = tid & 63;
    const int ln15 = lane & 15, quad = lane >> 4;
    const int m0 = blockIdx.x * 64 + wave * 16;
    const int n0 = blockIdx.y * 64;     // [0, 1536)

    floatx4 acc[4];
    for (int s = 0; s < 4; ++s) acc[s] = (floatx4){0.f, 0.f, 0.f, 0.f};

    for (int k0 = 0; k0 < 512; k0 += 32) {
        bf16x8 a = *(const bf16x8*)(xb + (m0 + ln15) * 512 + k0 + quad * 8);
        for (int s = 0; s < 4; ++s) {
            int cg = n0 + s * 16 + ln15;
            const bf16* bt = (cg < 768) ? (WlT + cg * 512) : (WcT + (cg - 768) * 512);
            bf16x8 b = *(const bf16x8*)(bt + k0 + quad * 8);
            acc[s] = mfma16(a, b, acc[s]);
        }
    }

    for (int s = 0; s < 4; ++s) {
        int cg = n0 + s * 16 + ln15;
        for (int r = 0; r < 4; ++r) {
            int row = m0 + quad * 4 + r;
            float v = acc[s][r];
            if (cg < 768) {
                v += b_l[cg];
                int qkv = cg >> 8, hh = (cg >> 6) & 3, d = cg & 63;
                if (qkv == 0)      lq[(hh * 4096 + row) * 64 + d] = (bf16)(v * 0.125f);
                else if (qkv == 1) lk[(hh * 4096 + row) * 64 + d] = (bf16)v;
                else               lv[(hh * 4096 + row) * 64 + d] = (bf16)v;
            } else {
                int c = cg - 768;
                v += b_c[c];
                int qkv = c >> 8, hh = (c >> 6) & 3, d = c & 63;
                if (qkv == 0)      cq[(hh * 4096 + row) * 64 + d] = (bf16)(v * 0.125f);
                else if (qkv == 1) ck[(hh * 4096 + row) * 64 + d] = (bf16)v;
                else               cv[(hh * 4096 + row) * 64 + d] = (bf16)v;
            }
        }
    }
}

// ---------------- saliency scores (pure fp32: top-k boundary needs precision) ----------------
// R12 lesson: 256-block variant = 1 block/CU = 11.5% occ = 125 us (latency-bound).
// This is the proven R8 shape: 1024 blocks x 4 rows, 16 waves/CU, W shared via L1.
__global__ __launch_bounds__(256) void k_scores(
    const float* __restrict__ x, const float* __restrict__ Ws1,  // [512][256]
    const float* __restrict__ bs1, const float* __restrict__ Ws2,  // [256]
    const float* __restrict__ bs2, float* __restrict__ scores)
{
    __shared__ float xs[4][512];   // 8 KB
    int row0 = blockIdx.x * 4;
    int t = threadIdx.x;
    for (int i = t; i < 512; i += 256) {
        int r = i >> 7, k4 = (i & 127) * 4;
        *(float4*)&xs[r][k4] = *(const float4*)&x[(row0 + r) * 512 + k4];
    }
    __syncthreads();
    int r = t >> 6, cb = (t & 63) * 4;
    float acc[4] = {0.f, 0.f, 0.f, 0.f};
    #pragma unroll 4
    for (int k = 0; k < 512; ++k) {
        float a = xs[r][k];
        float4 w = *(const float4*)(Ws1 + k * 256 + cb);
        acc[0] = fmaf(a, w.x, acc[0]); acc[1] = fmaf(a, w.y, acc[1]);
        acc[2] = fmaf(a, w.z, acc[2]); acc[3] = fmaf(a, w.w, acc[3]);
    }
    float s = 0.f;
    for (int j = 0; j < 4; ++j) {
        float v = acc[j] + bs1[cb + j];
        float g = 0.5f * v * (1.0f + erff(v * 0.70710678118654752f));  // exact gelu
        s = fmaf(g, Ws2[cb + j], s);
    }
    s += __shfl_xor(s, 1, 64);  s += __shfl_xor(s, 2, 64);
    s += __shfl_xor(s, 4, 64);  s += __shfl_xor(s, 8, 64);
    s += __shfl_xor(s, 16, 64); s += __shfl_xor(s, 32, 64);
    if ((t & 63) == 0) scores[row0 + r] = s + bs2[0];
}

// ---------------- exact top-819 via histogram select ----------------
__global__ __launch_bounds__(1024) void k_topk(const float* __restrict__ scores,
                                               int* __restrict__ sel, int* __restrict__ pos) {
    __shared__ unsigned ubuf[4096];
    __shared__ unsigned cga[2048], cgb[2048];
    __shared__ int bidx[1024];
    __shared__ int ctr, bctr, Bbin;
    int tid = threadIdx.x;
    if (tid == 0) { ctr = 0; bctr = 0; }
    for (int i = tid; i < 2048; i += 1024) cga[i] = 0u;
    __syncthreads();
    for (int i = tid; i < 4096; i += 1024) {
        unsigned s = __float_as_uint(scores[i]);
        unsigned u = (s & 0x80000000u) ? ~s : (s | 0x80000000u);   // order-preserving map
        ubuf[i] = u;
        pos[i] = -1;
        atomicAdd(&cga[u >> 21], 1u);
    }
    __syncthreads();
    unsigned* src = cga; unsigned* dst = cgb;
    for (int off = 1; off < 2048; off <<= 1) {
        for (int i = tid; i < 2048; i += 1024)
            dst[i] = src[i] + ((i + off < 2048) ? src[i + off] : 0u);
        __syncthreads();
        unsigned* tmp = src; src = dst; dst = tmp;
    }
    for (int b = tid; b < 2048; b += 1024) {
        unsigned ge = src[b];
        unsigned gt = (b < 2047) ? src[b + 1] : 0u;
        if (ge >= 819u && gt < 819u) Bbin = b;
    }
    __syncthreads();
    int B = Bbin;
    int countAbove = (B < 2047) ? (int)src[B + 1] : 0;
    int need = 819 - countAbove;
    for (int i = tid; i < 4096; i += 1024) {
        int b = (int)(ubuf[i] >> 21);
        if (b > B) {
            int slot = atomicAdd(&ctr, 1);
            sel[slot] = i;
            pos[i] = slot;
        } else if (b == B) {
            int ls = atomicAdd(&bctr, 1);
            if (ls < 1024) bidx[ls] = i;
        }
    }
    __syncthreads();
    int m = bctr;
    if (m <= 1024) {
        for (int e = tid; e < m; e += 1024) {
            int i = bidx[e];
            unsigned ui = ubuf[i];
            int rank = 0;
            for (int j = 0; j < m; ++j) {
                int ij = bidx[j];
                unsigned uj = ubuf[ij];
                rank += (uj > ui || (uj == ui && ij < i)) ? 1 : 0;
            }
            if (rank < need) { int slot = countAbove + rank; sel[slot] = i; pos[i] = slot; }
        }
    } else {
        for (int i = tid; i < 4096; i += 1024) {
            if ((int)(ubuf[i] >> 21) != B) continue;
            unsigned ui = ubuf[i];
            int rank = 0;
            for (int j = 0; j < 4096; ++j) {
                if ((int)(ubuf[j] >> 21) != B) continue;
                unsigned uj = ubuf[j];
                rank += (uj > ui || (uj == ui && j < i)) ? 1 : 0;
            }
            if (rank < need) { int slot = countAbove + rank; sel[slot] = i; pos[i] = slot; }
        }
    }
}

// ---------------- vt2: lv->lvT transpose tiles + content gather with fused cv transpose ------
// blocks [0,256): lvT tile b (tr = b&63, h = b>>6), R=4096
// blocks [256,312): gather tile: hh = (b-256)/14, tile = (b-256)%14, rows tile*64..+64 of 896
__global__ __launch_bounds__(256) void k_vt2(
    const bf16* __restrict__ lv, bf16* __restrict__ lvT,
    const bf16* __restrict__ ck, const bf16* __restrict__ cv,
    const int* __restrict__ sel,
    bf16* __restrict__ ckg, bf16* __restrict__ cvgT)
{
    __shared__ bf16 tile[64][66];
    int b = blockIdx.x;
    int t = threadIdx.x;
    int lane = t & 63, grp = t >> 6;
    if (b < 256) {
        int tr = b & 63, h = b >> 6;
        const bf16* s = lv + ((size_t)h * 4096 + tr * 64) * 64;
        #pragma unroll
        for (int rr = 0; rr < 16; ++rr) {
            int row = rr * 4 + grp;
            tile[row][lane] = s[row * 64 + lane];
        }
        __syncthreads();
        bf16* d = lvT + (size_t)h * 64 * 4096 + tr * 64;
        #pragma unroll
        for (int cc = 0; cc < 16; ++cc) {
            int col = cc * 4 + grp;
            d[(size_t)col * 4096 + lane] = tile[lane][col];
        }
    } else {
        int g = b - 256;
        int hh = g / 14, tl = g % 14;
        int r0 = tl * 64;
        #pragma unroll
        for (int rr = 0; rr < 16; ++rr) {
            int row = r0 + rr * 4 + grp;
            int src = (row < 819) ? sel[row] : -1;
            bf16 kv = (src >= 0) ? ck[(hh * 4096 + src) * 64 + lane] : (bf16)0.0f;
            bf16 vv = (src >= 0) ? cv[(hh * 4096 + src) * 64 + lane] : (bf16)0.0f;
            ckg[(hh * 896 + row) * 64 + lane] = kv;
            tile[rr * 4 + grp][lane] = vv;
        }
        __syncthreads();
        bf16* d = cvgT + (size_t)hh * 64 * 896 + r0;
        #pragma unroll
        for (int cc = 0; cc < 16; ++cc) {
            int col = cc * 4 + grp;
            d[(size_t)col * 896 + lane] = tile[lane][col];
        }
    }
}

// ---------------- pass 2b (fused pass 1): TWO m-tiles per wave (32 q-rows), K/V fragments
// shared between tiles. launch_bounds(256,4): 128-reg budget, no spill (R11 spilled at (256,5)).
// Local: 8-way key split (512 keys, 8 iters). Content: one block per head, all 896 keys,
// self-normalizing (writes cob + content lsum directly).
// grid (32, 36): y<32: local head y>>3, split (y&7)*512; y>=32: content head y-32.
__global__ __launch_bounds__(256, 4) void k_pass2b(
    const bf16* __restrict__ lq, const bf16* __restrict__ lk, const bf16* __restrict__ lvT,
    const bf16* __restrict__ cq, const bf16* __restrict__ ckg, const bf16* __restrict__ cvgT,
    float* __restrict__ partOL,   // [8][4096][256]
    float* __restrict__ partSL,   // [8][4][4096]
    float* __restrict__ lsum,     // [8][4096] (content rows 4..7 written here)
    bf16* __restrict__ cob)       // [4096][256] normalized content O
{
    __shared__ __align__(16) bf16 pbuf[4][2][2][16 * 40];  // [wave][mt][chain]
    int wave = threadIdx.x >> 6, lane = threadIdx.x & 63;
    int ln15 = lane & 15, quad = lane >> 4;
    int m0 = blockIdx.x * 128 + wave * 16;   // m-tile 0; m-tile 1 at m0+64
    int y = blockIdx.y;
    bool local = y < 32;
    int h     = local ? (y >> 3) : (y - 32);
    int split = local ? (y & 7) : 0;
    int NV    = local ? 4096 : 896;
    int kbeg  = local ? split * 512 : 0;
    int kcnt  = local ? 512 : 896;

    const bf16* Qb = (local ? lq : cq) + h * 4096 * 64;
    const bf16* Kh = (local ? lk : ckg) + h * NV * 64;
    const bf16* Vh = (local ? lvT : cvgT) + h * 64 * NV;

    bf16x8 af[2][2];
    #pragma unroll
    for (int mt = 0; mt < 2; ++mt) {
        af[mt][0] = *(const bf16x8*)(Qb + (m0 + mt * 64 + ln15) * 64 + quad * 8);
        af[mt][1] = *(const bf16x8*)(Qb + (m0 + mt * 64 + ln15) * 64 + 32 + quad * 8);
    }

    floatx4 o[2][4];
    #pragma unroll
    for (int mt = 0; mt < 2; ++mt)
        for (int ds = 0; ds < 4; ++ds) o[mt][ds] = (floatx4){0.f, 0.f, 0.f, 0.f};
    float se[2][4] = {{0.f, 0.f, 0.f, 0.f}, {0.f, 0.f, 0.f, 0.f}};

    for (int key0 = kbeg; key0 < kbeg + kcnt; key0 += 64) {
        // QK^T + exp + lsum for both chains x both m-tiles; K fragments shared across tiles
        #pragma unroll
        for (int c = 0; c < 2; ++c) {
            int kb = key0 + c * 32;
            #pragma unroll
            for (int s = 0; s < 2; ++s) {
                int kc = kb + s * 16;
                const bf16* krow = Kh + (kc + ln15) * 64;
                bf16x8 b0 = *(const bf16x8*)(krow + quad * 8);
                bf16x8 b1 = *(const bf16x8*)(krow + 32 + quad * 8);
                bool valid = local || (kc + ln15) < 819;
                #pragma unroll
                for (int mt = 0; mt < 2; ++mt) {
                    floatx4 z0 = (floatx4){0.f, 0.f, 0.f, 0.f};
                    floatx4 z1 = (floatx4){0.f, 0.f, 0.f, 0.f};
                    z0 = mfma16(af[mt][0], b0, z0);
                    z1 = mfma16(af[mt][1], b1, z1);
                    bf16* pb = &pbuf[wave][mt][c][0];
                    #pragma unroll
                    for (int r = 0; r < 4; ++r) {
                        float p = valid ? __expf(fminf(z0[r] + z1[r], 60.f)) : 0.0f;
                        se[mt][r] += p;                                    // pass-1 fused
                        pb[(quad * 4 + r) * 40 + s * 16 + ln15] = (bf16)p; // unnormalized
                    }
                }
            }
        }
        // P@V for both chains; V fragments shared across the two m-tiles
        #pragma unroll
        for (int c = 0; c < 2; ++c) {
            int kb = key0 + c * 32;
            bf16x8 ap0 = *(const bf16x8*)(&pbuf[wave][0][c][0] + ln15 * 40 + quad * 8);
            bf16x8 ap1 = *(const bf16x8*)(&pbuf[wave][1][c][0] + ln15 * 40 + quad * 8);
            #pragma unroll
            for (int ds = 0; ds < 4; ++ds) {
                bf16x8 vb = *(const bf16x8*)(Vh + (ds * 16 + ln15) * NV + kb + quad * 8);
                o[0][ds] = mfma16(ap0, vb, o[0][ds]);
                o[1][ds] = mfma16(ap1, vb, o[1][ds]);
            }
        }
    }

    if (local) {
        float* ps = partSL + (split * 4 + h) * 4096;
        #pragma unroll
        for (int mt = 0; mt < 2; ++mt)
            for (int r = 0; r < 4; ++r) {
                float s = se[mt][r];
                s += __shfl_xor(s, 1, 64);
                s += __shfl_xor(s, 2, 64);
                s += __shfl_xor(s, 4, 64);
                s += __shfl_xor(s, 8, 64);
                if (ln15 == 0) ps[m0 + mt * 64 + quad * 4 + r] = s;
            }
        float* ob = partOL + (size_t)split * (4096 * 256);
        #pragma unroll
        for (int mt = 0; mt < 2; ++mt)
            for (int ds = 0; ds < 4; ++ds)
                for (int r = 0; r < 4; ++r)
                    ob[(m0 + mt * 64 + quad * 4 + r) * 256 + h * 64 + ds * 16 + ln15] =
                        o[mt][ds][r];
    } else {
        #pragma unroll
        for (int mt = 0; mt < 2; ++mt) {
            float rl[4];
            #pragma unroll
            for (int r = 0; r < 4; ++r) {
                float s = se[mt][r];
                s += __shfl_xor(s, 1, 64);
                s += __shfl_xor(s, 2, 64);
                s += __shfl_xor(s, 4, 64);
                s += __shfl_xor(s, 8, 64);
                if (ln15 == 0) lsum[(4 + h) * 4096 + m0 + mt * 64 + quad * 4 + r] = s;
                rl[r] = 1.0f / fmaxf(s, 1e-30f);
            }
            #pragma unroll
            for (int ds = 0; ds < 4; ++ds)
                for (int r = 0; r < 4; ++r)
                    cob[(m0 + mt * 64 + quad * 4 + r) * 256 + h * 64 + ds * 16 + ln15] =
                        (bf16)(o[mt][ds][r] * rl[r]);
        }
    }
}

// ---------------- reduce local partials (8 splits): lsum local rows + normalized lob ---------
__global__ __launch_bounds__(256) void k_reduce2(
    const float* __restrict__ partOL, const float* __restrict__ partSL,
    float* __restrict__ lsum, bf16* __restrict__ lob)
{
    int t = threadIdx.x;
    int q0 = blockIdx.x * 4;
    int r = t >> 6, cc = (t & 63) * 4;
    int q = q0 + r;
    int h = cc >> 6;

    float sl = 0.f;
    #pragma unroll
    for (int s = 0; s < 8; ++s) sl += partSL[(s * 4 + h) * 4096 + q];
    float rll = 1.0f / fmaxf(sl, 1e-30f);
    float a0 = 0.f, a1 = 0.f, a2 = 0.f, a3 = 0.f;
    #pragma unroll
    for (int s = 0; s < 8; ++s) {
        float4 v = *(const float4*)(partOL + (size_t)s * 1048576 + q * 256 + cc);
        a0 += v.x; a1 += v.y; a2 += v.z; a3 += v.w;
    }
    bf16x4 ol;
    ol[0] = (bf16)(a0 * rll); ol[1] = (bf16)(a1 * rll);
    ol[2] = (bf16)(a2 * rll); ol[3] = (bf16)(a3 * rll);
    *(bf16x4*)(lob + q * 256 + cc) = ol;

    if (t < 16) {
        int h8 = t >> 2, rr = t & 3, qq = q0 + rr;
        float s = 0.f;
        #pragma unroll
        for (int sp = 0; sp < 8; ++sp) s += partSL[(sp * 4 + h8) * 4096 + qq];
        lsum[h8 * 4096 + qq] = s;
    }
}

// ---------------- pass 2a: head-mean attn write only ----------------
// grid (64, 20): y<16: local, span y*256 (8 iters); y>=16: content, span (y-16)*224 (7 iters)
__global__ __launch_bounds__(256) void k_pass2a(
    const bf16* __restrict__ lq, const bf16* __restrict__ lk,
    const bf16* __restrict__ cq, const bf16* __restrict__ ckg,
    const float* __restrict__ lsum,
    float* __restrict__ attn_local,     // [4096][4096]
    bf16* __restrict__ pcomp)           // [4096][832] compact content probs
{
    int wave = threadIdx.x >> 6, lane = threadIdx.x & 63;
    int ln15 = lane & 15, quad = lane >> 4;
    int m0 = blockIdx.x * 64 + wave * 16;
    int y = blockIdx.y;
    bool local = y < 16;
    const bf16* Q  = local ? lq : cq;
    const bf16* Kt = local ? lk : ckg;
    int NV = local ? 4096 : 896;
    int kbeg = local ? y * 256 : (y - 16) * 224;
    int kend = kbeg + (local ? 256 : 224);
    int hbase = local ? 0 : 4;

    bf16x8 af[4][2];
    #pragma unroll
    for (int h2 = 0; h2 < 4; ++h2)
        for (int ks = 0; ks < 2; ++ks)
            af[h2][ks] = *(const bf16x8*)(Q + (h2 * 4096 + m0 + ln15) * 64 + ks * 32 + quad * 8);

    float rl[4][4];   // 0.25/denominator: head-mean factor folded in
    #pragma unroll
    for (int h2 = 0; h2 < 4; ++h2)
        for (int r = 0; r < 4; ++r)
            rl[h2][r] = 0.25f / fmaxf(lsum[(hbase + h2) * 4096 + m0 + quad * 4 + r], 1e-30f);

    for (int key0 = kbeg; key0 < kend; key0 += 32) {
        float pm[2][4] = {{0.f, 0.f, 0.f, 0.f}, {0.f, 0.f, 0.f, 0.f}};
        #pragma unroll
        for (int h2 = 0; h2 < 4; ++h2) {
            #pragma unroll
            for (int s = 0; s < 2; ++s) {
                int kc = key0 + s * 16;
                const bf16* krow = Kt + (h2 * NV + kc + ln15) * 64;
                floatx4 z0 = (floatx4){0.f, 0.f, 0.f, 0.f};
                floatx4 z1 = (floatx4){0.f, 0.f, 0.f, 0.f};
                z0 = mfma16(af[h2][0], *(const bf16x8*)(krow + quad * 8), z0);
                z1 = mfma16(af[h2][1], *(const bf16x8*)(krow + 32 + quad * 8), z1);
                bool valid = local || (kc + ln15) < 819;
                if (valid)
                    for (int r = 0; r < 4; ++r)
                        pm[s][r] += __expf(fminf(z0[r] + z1[r], 60.f)) * rl[h2][r];
            }
        }
        if (local) {
            #pragma unroll
            for (int s = 0; s < 2; ++s)
                for (int r = 0; r < 4; ++r)
                    attn_local[(m0 + quad * 4 + r) * 4096 + key0 + s * 16 + ln15] = pm[s][r];
        } else {
            #pragma unroll
            for (int s = 0; s < 2; ++s) {
                int kc = key0 + s * 16 + ln15;
                if (kc < 832)
                    for (int r = 0; r < 4; ++r)
                        pcomp[(m0 + quad * 4 + r) * 832 + kc] = (bf16)(pm[s][r]);
            }
        }
    }
}

// ---------------- expand + proj weight transposes, one kernel ----------------
// blocks [0,4096): expand row b; [4096,4224): WlpT tile; [4224,4352): WcpT tile
__global__ __launch_bounds__(256) void k_expand2(
    const bf16* __restrict__ pcomp, const int* __restrict__ pos,
    const float* __restrict__ W_lproj, const float* __restrict__ W_cproj,
    bf16* __restrict__ WlpT, bf16* __restrict__ WcpT,
    float* __restrict__ attn_content)
{
    __shared__ float tile[32][33];
    int b = blockIdx.x;
    if (b < 4096) {
        int c0 = threadIdx.x * 16;
        const bf16* prow = pcomp + b * 832;
        float vals[16];
        #pragma unroll
        for (int j = 0; j < 16; ++j) {
            int p = pos[c0 + j];
            vals[j] = (p >= 0) ? (float)prow[p] : 0.0f;
        }
        float* dst = attn_content + (size_t)b * 4096 + c0;
        *(float4*)(dst)      = (float4){vals[0], vals[1], vals[2], vals[3]};
        *(float4*)(dst + 4)  = (float4){vals[4], vals[5], vals[6], vals[7]};
        *(float4*)(dst + 8)  = (float4){vals[8], vals[9], vals[10], vals[11]};
        *(float4*)(dst + 12) = (float4){vals[12], vals[13], vals[14], vals[15]};
    } else if (b < 4224) {
        int g = b - 4096;
        transpose_tile(W_lproj, WlpT, 256, 512, g / 16, g % 16, tile);
    } else {
        int g = b - 4224;
        transpose_tile(W_cproj, WcpT, 256, 512, g / 16, g % 16, tile);
    }
}

// ---------------- output projection (bf16 MFMA, bf16 A direct) ----------------
// grid (64,16): n0 = 32-col blocks -> 4096 waves = 4 waves/SIMD.
__global__ __launch_bounds__(256) void k_proj(
    const bf16* __restrict__ lob, const bf16* __restrict__ cob,
    const bf16* __restrict__ WlpT, const bf16* __restrict__ WcpT,   // [512][256] bf16
    const float* __restrict__ bl, const float* __restrict__ bc,
    float* __restrict__ out)
{
    const int tid = threadIdx.x;
    const int wave = tid >> 6, lane = tid & 63;
    const int ln15 = lane & 15, quad = lane >> 4;
    const int m0 = blockIdx.x * 64 + wave * 16;
    const int n0 = blockIdx.y * 32;     // [0, 512)

    floatx4 acc[2];
    acc[0] = (floatx4){0.f, 0.f, 0.f, 0.f};
    acc[1] = (floatx4){0.f, 0.f, 0.f, 0.f};

    for (int k0 = 0; k0 < 256; k0 += 32) {
        bf16x8 al = *(const bf16x8*)(lob + (m0 + ln15) * 256 + k0 + quad * 8);
        bf16x8 ac = *(const bf16x8*)(cob + (m0 + ln15) * 256 + k0 + quad * 8);
        #pragma unroll
        for (int s = 0; s < 2; ++s) {
            int c = n0 + s * 16 + ln15;
            acc[s] = mfma16(al, *(const bf16x8*)(WlpT + c * 256 + k0 + quad * 8), acc[s]);
            acc[s] = mfma16(ac, *(const bf16x8*)(WcpT + c * 256 + k0 + quad * 8), acc[s]);
        }
    }
    #pragma unroll
    for (int s = 0; s < 2; ++s) {
        int c = n0 + s * 16 + ln15;
        float bias = bl[c] + bc[c];
        for (int r = 0; r < 4; ++r)
            out[(m0 + quad * 4 + r) * 512 + c] = acc[s][r] + bias;
    }
}

// ---------------- workspace layout (bytes), total 26,251,264 (proven-safe) ----------------
#define OFF_WLQKVT  0L            //  768x512 bf16
#define OFF_WCQKVT  786432L       //  768x512 bf16
#define OFF_LQ      1572864L      //  4x4096x64 bf16
#define OFF_LK      3670016L
#define OFF_LVT     5767168L
#define OFF_CQ      7864320L
#define OFF_CK      9961472L
#define OFF_CV      12058624L
#define OFF_PCOMP   9961472L      // aliases ck/cv (disjoint lifetime)
#define OFF_CKG     16777216L     //  4x896x64 bf16
#define OFF_CVGT    17235968L     //  4x64x896 bf16
#define OFF_WLPT    16777216L     //  aliases ckg (written in k_expand2, post-pass2a)
#define OFF_WCPT    17039360L     //  aliases ckg/cvgT (written in k_expand2, post-pass2a)
#define OFF_SCORES  17694720L     //  4096 f32
#define OFF_SEL     17711104L
#define OFF_POS     17715200L
#define OFF_LSUM    17731584L     //  8x4096 f32 (content rows by pass2b, local rows by reduce2)
#define OFF_LO      17862656L     //  region: xb (4MB bf16, prep..qkv) then lob (2MB bf16, reduce2..proj)
#define OFF_CO      22056960L     //  region: lv (2MB bf16, qkv..vt2) then cob (2MB bf16, pass2b..proj)
#define WS_TOTAL    26251264L
// Partials (32.5 MB) live in the attn_content output region (dead until k_expand2):
//   partOL [8][4096][256] f32 @ attn_content + 0           (8,388,608 floats)
//   partSL [8][4][4096]  f32  @ attn_content + 8,388,608   (131,072 floats)

extern "C" void kernel_launch(void* const* d_in, const int* in_sizes, int n_in,
                              void* d_out, int out_size, void* d_ws, size_t ws_size,
                              hipStream_t stream) {
    if (ws_size < (size_t)WS_TOTAL) return;  // diagnostic signature: absmax == 4.077e-2

    const float* x       = (const float*)d_in[0];
    const float* W_lqkv  = (const float*)d_in[1];
    const float* b_lqkv  = (const float*)d_in[2];
    const float* W_cqkv  = (const float*)d_in[3];
    const float* b_cqkv  = (const float*)d_in[4];
    const float* W_lproj = (const float*)d_in[5];
    const float* b_lproj = (const float*)d_in[6];
    const float* W_cproj = (const float*)d_in[7];
    const float* b_cproj = (const float*)d_in[8];
    const float* W_s1    = (const float*)d_in[9];
    const float* b_s1    = (const float*)d_in[10];
    const float* W_s2    = (const float*)d_in[11];
    const float* b_s2    = (const float*)d_in[12];

    char* ws = (char*)d_ws;
    bf16* WlqkvT  = (bf16*)(ws + OFF_WLQKVT);
    bf16* WcqkvT  = (bf16*)(ws + OFF_WCQKVT);
    bf16* lq    = (bf16*)(ws + OFF_LQ);
    bf16* lk    = (bf16*)(ws + OFF_LK);
    bf16* lvT   = (bf16*)(ws + OFF_LVT);
    bf16* cq    = (bf16*)(ws + OFF_CQ);
    bf16* ck    = (bf16*)(ws + OFF_CK);
    bf16* cv    = (bf16*)(ws + OFF_CV);
    bf16* pcomp = (bf16*)(ws + OFF_PCOMP);
    bf16* ckg   = (bf16*)(ws + OFF_CKG);
    bf16* cvgT  = (bf16*)(ws + OFF_CVGT);
    bf16* WlpT  = (bf16*)(ws + OFF_WLPT);
    bf16* WcpT  = (bf16*)(ws + OFF_WCPT);
    float* scores  = (float*)(ws + OFF_SCORES);
    int*   sel     = (int*)(ws + OFF_SEL);
    int*   pos     = (int*)(ws + OFF_POS);
    float* lsum    = (float*)(ws + OFF_LSUM);
    bf16*  xb      = (bf16*)(ws + OFF_LO);     // alias: dead once k_qkv done
    bf16*  lob     = (bf16*)(ws + OFF_LO);     // written by k_reduce2 (after xb dead)
    bf16*  lv      = (bf16*)(ws + OFF_CO);     // alias: dead once k_vt2 done
    bf16*  cob     = (bf16*)(ws + OFF_CO);     // written by k_pass2b (after lv dead)

    float* outp = (float*)d_out;
    float* attn_local   = outp + 2097152;              // 4096*512
    float* attn_content = attn_local + 4096 * 4096;
    float* partOL = attn_content;                      // scratch in output region
    float* partSL = attn_content + 8388608;

    k_prep<<<1792, 256, 0, stream>>>(W_lqkv, W_cqkv, x, WlqkvT, WcqkvT, xb);
    k_qkv<<<dim3(64, 24), 256, 0, stream>>>(xb, WlqkvT, WcqkvT, b_lqkv, b_cqkv,
                                            lq, lk, lv, cq, ck, cv);
    k_scores<<<1024, 256, 0, stream>>>(x, W_s1, b_s1, W_s2, b_s2, scores);
    k_topk<<<1, 1024, 0, stream>>>(scores, sel, pos);
    k_vt2<<<312, 256, 0, stream>>>(lv, lvT, ck, cv, sel, ckg, cvgT);
    // fused attention core: 2 m-tiles/wave, shared K/V fragments, no atomics, no pre-zero
    k_pass2b<<<dim3(32, 36), 256, 0, stream>>>(lq, lk, lvT, cq, ckg, cvgT,
                                               partOL, partSL, lsum, cob);
    k_reduce2<<<1024, 256, 0, stream>>>(partOL, partSL, lsum, lob);
    k_pass2a<<<dim3(64, 20), 256, 0, stream>>>(lq, lk, cq, ckg, lsum,
                                               attn_local, pcomp);
    k_expand2<<<4352, 256, 0, stream>>>(pcomp, pos, W_lproj, W_cproj,
                                        WlpT, WcpT, attn_content);
    k_proj<<<dim3(64, 16), 256, 0, stream>>>(lob, cob, WlpT, WcpT, b_lproj, b_cproj, outp);
}